// Round 7
// baseline (356.980 us; speedup 1.0000x reference)
//
#include <hip/hip_runtime.h>
#include <hip/hip_bf16.h>
#include <hip/hip_fp16.h>

// GCN, dis-folded: A_norm = D^-1/2 (A_w + I) D^-1/2; CSR stores raw w.
// R19: GEMMs were latency-bound at VGPR=48 (R18: MfmaUtil 2.5%, VALUBusy 6%,
//      HBM 11%, occ 33% -- ~2 loads in flight/wave => ~860 GB/s). Restructure:
//      all 8 A-loads issued up-front, B loaded in per-t batches of 4 so t+1
//      loads overlap t's MFMAs. Identical FMA order (bit-identical output).
//      Prop split kept for observability. Rest unchanged from R18.

#define FEAT 128
#define BSH 8                 // bucket shift
#define BCAP 8192             // entries per bucket (mean 4092)

typedef union { int2 i2; long long u; struct { int s; float w; } e; } EdgePair;
typedef union { unsigned u; __half2 h2; } H2U;
typedef _Float16 f16x8 __attribute__((ext_vector_type(8)));
typedef float f32x4 __attribute__((ext_vector_type(4)));
typedef float f32x2 __attribute__((ext_vector_type(2)));

__device__ __forceinline__ unsigned pack2h(float a, float b) {
    return (unsigned)__half_as_ushort(__float2half_rn(a)) |
           ((unsigned)__half_as_ushort(__float2half_rn(b)) << 16);   // RNE both
}

__device__ __forceinline__ unsigned char to_fp8(float v) {
    int pk = __builtin_amdgcn_cvt_pk_fp8_f32(v, v, 0, false);   // RNE, sat
    return (unsigned char)(pk & 0xFF);
}

// ---------------- pass 1: bin edges by dst>>8, LDS-staged coalesced output ----------------
__global__ __launch_bounds__(256) void bin1_kernel(const int* __restrict__ src,
                                                   const int* __restrict__ dst,
                                                   const float* __restrict__ w,
                                                   int* __restrict__ gcnt,
                                                   int2* __restrict__ bins,
                                                   int E_, int NB) {
    __shared__ int lh[392], lofs[392], lbase[392], lcur[392];
    __shared__ unsigned sU[4096];
    __shared__ float    sW[4096];
    __shared__ unsigned short sB[4096];
    const int CHUNK = 4096;
    int base = blockIdx.x * CHUNK;
    int tid = threadIdx.x;
    for (int t = tid; t < NB; t += 256) { lh[t] = 0; lcur[t] = 0; }
    __syncthreads();
    int ds[16];
#pragma unroll
    for (int j = 0; j < 16; ++j) {
        int e = base + j * 256 + tid;
        ds[j] = (e < E_) ? dst[e] : -1;
        if (ds[j] >= 0) atomicAdd(&lh[ds[j] >> BSH], 1);
    }
    __syncthreads();
    // parallel exclusive prefix: thread t sums lh[0..t-1] (loads pipeline)
    for (int t = tid; t < NB; t += 256) {
        int run = 0;
        for (int i = 0; i < t; ++i) run += lh[i];
        lofs[t] = run;
    }
    __syncthreads();
    for (int t = tid; t < NB; t += 256)
        if (lh[t] > 0) lbase[t] = atomicAdd(&gcnt[t], lh[t]);
    __syncthreads();
    // place edges compactly into LDS staging, bucket-sorted
#pragma unroll
    for (int j = 0; j < 16; ++j) {
        int e = base + j * 256 + tid;
        if (ds[j] >= 0) {
            int b = ds[j] >> BSH;
            int r = atomicAdd(&lcur[b], 1);
            int s = lofs[b] + r;
            sU[s] = (unsigned)src[e] | ((unsigned)(ds[j] & 255) << 20);
            sW[s] = w[e];
            sB[s] = (unsigned short)b;
        }
    }
    __syncthreads();
    // linear copy-out: consecutive threads -> consecutive slots of each bucket run
    int total = min(CHUNK, E_ - base);
    for (int s = tid; s < total; s += 256) {
        int b = sB[s];
        int g = lbase[b] + (s - lofs[b]);
        if (g < BCAP) {
            int2 val; val.x = (int)sU[s]; val.y = __float_as_int(sW[s]);
            bins[(size_t)b * BCAP + g] = val;
        }
    }
}

// ---------------- fused CSR build: self-prefix + histogram + scan + rp/dis +
//                  LDS-staged scatter + coalesced copy-out ----------------
// cv entry: (f16bits(w) << 17) | src   (w in [0,1] -> f16 bits <= 0x3C00, 15 bits)
__global__ __launch_bounds__(256) void buildcsr_kernel(const int2* __restrict__ bins,
                                                       const int* __restrict__ gcnt,
                                                       int* __restrict__ rp,
                                                       float* __restrict__ dis,
                                                       unsigned* __restrict__ cv, int n) {
    __shared__ int lh[256];
    __shared__ float wsum[256];
    __shared__ int sc[256];
    __shared__ int lcur[256];
    __shared__ int red[256];
    __shared__ unsigned scv[BCAP + 256];
    int b = blockIdx.x;
    int tid = threadIdx.x;
    int node0 = b << BSH;
    int node = node0 + tid;
    bool valid = node < n;
    lh[tid] = 0;
    wsum[tid] = 1.0f;   // self-loop weight
    // self-computed exclusive prefix over buckets < b (gcnt L2-hot after bin1)
    int part = 0;
    for (int i = tid; i < b; i += 256)
        part += min(gcnt[i], BCAP) + min(256, n - (i << BSH));
    red[tid] = part;
    __syncthreads();
    for (int off = 128; off > 0; off >>= 1) {
        if (tid < off) red[tid] += red[tid + off];
        __syncthreads();
    }
    int base = red[0];
    int m = min(gcnt[b], BCAP);
    int nvalid = min(256, n - node0);
    if (b == (int)gridDim.x - 1 && tid == 0)
        rp[n] = base + m + nvalid;
    const int2* bp = bins + (size_t)b * BCAP;
    for (int i = tid; i < m; i += 256) {
        int2 raw = bp[i];
        unsigned pk = (unsigned)raw.x;
        int dlo = pk >> 20;
        atomicAdd(&lh[dlo], 1);
        atomicAdd(&wsum[dlo], __int_as_float(raw.y));
    }
    __syncthreads();
    int cnt_t = valid ? (lh[tid] + 1) : 0;   // +1 self-loop
    sc[tid] = cnt_t;
    __syncthreads();
    for (int off = 1; off < 256; off <<= 1) {
        int x = (tid >= off) ? sc[tid - off] : 0;
        __syncthreads();
        sc[tid] += x;
        __syncthreads();
    }
    int excl = sc[tid] - cnt_t;
    if (valid) {
        rp[node] = base + excl;
        dis[node] = rsqrtf(fmaxf(wsum[tid], 1e-12f));
    }
    lcur[tid] = excl;                        // LOCAL positions for staging
    __syncthreads();
    for (int i = tid; i < m; i += 256) {
        int2 raw = bp[i];                    // second read: L2-hot
        unsigned pk = (unsigned)raw.x;
        int dlo = pk >> 20;
        int pos = atomicAdd(&lcur[dlo], 1);
        unsigned hw = (unsigned)__half_as_ushort(__float2half_rn(__int_as_float(raw.y)));
        scv[pos] = (hw << 17) | (pk & 0x1FFFF);
    }
    __syncthreads();
    if (valid) {                             // self-loop entry, w = 1 -> f16 0x3C00
        int pos = atomicAdd(&lcur[tid], 1);
        scv[pos] = (0x3C00u << 17) | (unsigned)node;
    }
    __syncthreads();
    // contiguous coalesced copy-out of the whole bucket range
    int total = m + nvalid;
    for (int s = tid; s < total; s += 256)
        cv[base + s] = scv[s];
}

// ---------------- merged tiny preps ----------------
// blocks [0,64): Wt0; [64,128): Wt1; 128: Wc+bc+gcnt-zero; [129, 129+nbg): gbound
__global__ __launch_bounds__(256) void prep_kernel(const float* __restrict__ W0,
                                                   const float* __restrict__ W1,
                                                   const float* __restrict__ W2,
                                                   const float* __restrict__ Wp,
                                                   const float* __restrict__ b2,
                                                   const float* __restrict__ bp,
                                                   const int* __restrict__ batch,
                                                   _Float16* __restrict__ Wt0,
                                                   _Float16* __restrict__ Wt1,
                                                   float* __restrict__ Wc,
                                                   float* __restrict__ bc,
                                                   int* __restrict__ gstart,
                                                   int* __restrict__ gcnt,
                                                   int n, int G_, int NB) {
    int blk = blockIdx.x;
    if (blk < 64) {
        int tid = blk * 256 + threadIdx.x;
        int nn = tid >> 7, k = tid & 127;
        Wt0[nn * 128 + k] = (_Float16)W0[k * 128 + nn];
    } else if (blk < 128) {
        int tid = (blk - 64) * 256 + threadIdx.x;
        int nn = tid >> 7, k = tid & 127;
        Wt1[nn * 128 + k] = (_Float16)W1[k * 128 + nn];
    } else if (blk == 128) {
        for (int tid = threadIdx.x; tid < 512; tid += 256) {
            int c = tid >> 2, k = tid & 3;
            float s = 0.f;
            for (int j = 0; j < 200; ++j) s = fmaf(W2[c * 200 + j], Wp[j * 4 + k], s);
            Wc[tid] = s;
        }
        if (threadIdx.x < 4) {
            float s = bp[threadIdx.x];
            for (int j = 0; j < 200; ++j) s = fmaf(b2[j], Wp[j * 4 + threadIdx.x], s);
            bc[threadIdx.x] = s;
        }
        for (int i = threadIdx.x; i < NB; i += 256) gcnt[i] = 0;
    } else {
        int i = (blk - 129) * 256 + threadIdx.x;
        if (i >= n) return;
        int b = batch[i];
        int prev = (i == 0) ? -1 : batch[i - 1];
        for (int g = prev + 1; g <= b; ++g) gstart[g] = i;
        if (i == n - 1) {
            for (int g = b + 1; g <= G_; ++g) gstart[g] = n;
        }
    }
}

// ---------------- MFMA GEMM: C_fp8[M x 128] = rowscale .* (A @ W), Wt[n][k] f16 ----------------
// Pipelined: all 8 A-loads issued before use; B loaded in per-t batches of 4
// (t+1 batch overlaps t's MFMAs). Same FMA order as R18 -> bit-identical.
__global__ __launch_bounds__(256) void gemm1_mfma(const float* __restrict__ A,
                                                  const _Float16* __restrict__ Wt,
                                                  const float* __restrict__ rowscale,
                                                  unsigned char* __restrict__ C, int M) {
    int wid = threadIdx.x >> 6, lane = threadIdx.x & 63;
    int quad = lane >> 4, l16 = lane & 15;
    int row0 = blockIdx.x * 64 + wid * 16;
    int arow = row0 + l16; if (arow >= M) arow = M - 1;   // clamp: pollutes only discarded D rows
    const float* abase = A + (size_t)arow * 128 + quad * 8;
    float4 a0[4], a1[4];
#pragma unroll
    for (int kc = 0; kc < 4; ++kc) {            // 8 independent loads in flight
        a0[kc] = *(const float4*)(abase + kc * 32);
        a1[kc] = *(const float4*)(abase + kc * 32 + 4);
    }
    f16x8 af[4];
#pragma unroll
    for (int kc = 0; kc < 4; ++kc)
        af[kc] = (f16x8){ (_Float16)a0[kc].x, (_Float16)a0[kc].y, (_Float16)a0[kc].z, (_Float16)a0[kc].w,
                          (_Float16)a1[kc].x, (_Float16)a1[kc].y, (_Float16)a1[kc].z, (_Float16)a1[kc].w };
    f32x4 acc[8];
#pragma unroll
    for (int t = 0; t < 8; ++t) acc[t] = (f32x4){0.f, 0.f, 0.f, 0.f};
    const _Float16* wbase = Wt + (size_t)l16 * 128 + quad * 8;
#pragma unroll
    for (int t = 0; t < 8; ++t) {
        f16x8 bf[4];
#pragma unroll
        for (int kc = 0; kc < 4; ++kc)
            bf[kc] = *(const f16x8*)(wbase + (size_t)t * 16 * 128 + kc * 32);
#pragma unroll
        for (int kc = 0; kc < 4; ++kc)
            acc[t] = __builtin_amdgcn_mfma_f32_16x16x32_f16(af[kc], bf[kc], acc[t], 0, 0, 0);
    }
    int orow0 = row0 + quad * 4;
#pragma unroll
    for (int r = 0; r < 4; ++r) {
        int orow = orow0 + r;
        if (orow < M) {
            float sc = rowscale[orow];
#pragma unroll
            for (int t = 0; t < 8; ++t)
                C[(size_t)orow * 128 + t * 16 + l16] = to_fp8(acc[t][r] * sc);
        }
    }
}

__global__ __launch_bounds__(256) void gemm2_mfma(const unsigned short* __restrict__ A,
                                                  const _Float16* __restrict__ Wt,
                                                  const float* __restrict__ rowscale,
                                                  unsigned char* __restrict__ C, int M) {
    int wid = threadIdx.x >> 6, lane = threadIdx.x & 63;
    int quad = lane >> 4, l16 = lane & 15;
    int row0 = blockIdx.x * 64 + wid * 16;
    int arow = row0 + l16; if (arow >= M) arow = M - 1;
    const _Float16* abase = (const _Float16*)A + (size_t)arow * 128 + quad * 8;
    f16x8 af[4];
#pragma unroll
    for (int kc = 0; kc < 4; ++kc)              // 4 independent loads in flight
        af[kc] = *(const f16x8*)(abase + kc * 32);
    f32x4 acc[8];
#pragma unroll
    for (int t = 0; t < 8; ++t) acc[t] = (f32x4){0.f, 0.f, 0.f, 0.f};
    const _Float16* wbase = Wt + (size_t)l16 * 128 + quad * 8;
#pragma unroll
    for (int t = 0; t < 8; ++t) {
        f16x8 bf[4];
#pragma unroll
        for (int kc = 0; kc < 4; ++kc)
            bf[kc] = *(const f16x8*)(wbase + (size_t)t * 16 * 128 + kc * 32);
#pragma unroll
        for (int kc = 0; kc < 4; ++kc)
            acc[t] = __builtin_amdgcn_mfma_f32_16x16x32_f16(af[kc], bf[kc], acc[t], 0, 0, 0);
    }
    int orow0 = row0 + quad * 4;
#pragma unroll
    for (int r = 0; r < 4; ++r) {
        int orow = orow0 + r;
        if (orow < M) {
            float sc = rowscale[orow];
#pragma unroll
            for (int t = 0; t < 8; ++t)
                C[(size_t)orow * 128 + t * 16 + l16] = to_fp8(acc[t][r] * sc);
        }
    }
}

// ---------------- CSR propagate, 128 fp8 feats (layer 1), node range [off,lim) ----------------
// wave/node; half-wave per edge, 32 lanes x 4 fp8. Full 16-edge rounds carry
// no clamp/cndmask; only the tail round does. f32x2 packed accumulate.
__global__ __launch_bounds__(256) void prop_kernel(const int* __restrict__ rp,
                                                   const unsigned* __restrict__ cv,
                                                   const float* __restrict__ dis,
                                                   const unsigned char* __restrict__ t8,
                                                   const float* __restrict__ bias,
                                                   unsigned short* __restrict__ out,
                                                   int off, int lim) {
    int wv = off + ((blockIdx.x * blockDim.x + threadIdx.x) >> 6);
    int lane = threadIdx.x & 63;
    if (wv >= lim) return;
    int half = lane >> 5, l5 = lane & 31;
    int beg = rp[wv], end = rp[wv + 1];
    const unsigned char* tb = t8 + 4 * l5;
    f32x2 aL[4], aH[4];
#pragma unroll
    for (int j = 0; j < 4; ++j) { aL[j] = (f32x2){0.f, 0.f}; aH[j] = (f32x2){0.f, 0.f}; }
    int deg = end - beg;
    int nfull = deg & ~15;
    int p = beg;
    for (; p < beg + nfull; p += 16) {
#pragma unroll
        for (int jj = 0; jj < 8; ++jj) {
            unsigned e = cv[p + 2 * jj + half];
            unsigned v = *(const unsigned*)(tb + ((size_t)(e & 0x1FFFF) << 7));
            float w = __half2float(__ushort_as_half((unsigned short)(e >> 17)));
            f32x2 w2 = {w, w};
            f32x2 lo = __builtin_amdgcn_cvt_pk_f32_fp8((int)v, false);
            f32x2 hi = __builtin_amdgcn_cvt_pk_f32_fp8((int)v, true);
            aL[jj & 3] = lo * w2 + aL[jj & 3];
            aH[jj & 3] = hi * w2 + aH[jj & 3];
        }
    }
    if (p < end) {
        int last = end - 1;
#pragma unroll
        for (int jj = 0; jj < 8; ++jj) {
            int idx = p + 2 * jj + half;
            unsigned e = cv[min(idx, last)];
            unsigned v = *(const unsigned*)(tb + ((size_t)(e & 0x1FFFF) << 7));
            float w = __half2float(__ushort_as_half((unsigned short)(e >> 17)));
            w = (idx < end) ? w : 0.f;
            f32x2 w2 = {w, w};
            f32x2 lo = __builtin_amdgcn_cvt_pk_f32_fp8((int)v, false);
            f32x2 hi = __builtin_amdgcn_cvt_pk_f32_fp8((int)v, true);
            aL[jj & 3] = lo * w2 + aL[jj & 3];
            aH[jj & 3] = hi * w2 + aH[jj & 3];
        }
    }
    f32x2 sL = (aL[0] + aL[1]) + (aL[2] + aL[3]);
    f32x2 sH = (aH[0] + aH[1]) + (aH[2] + aH[3]);
    float s0 = sL[0], s1 = sL[1], s2 = sH[0], s3 = sH[1];
    s0 += __shfl_xor(s0, 32, 64);
    s1 += __shfl_xor(s1, 32, 64);
    s2 += __shfl_xor(s2, 32, 64);
    s3 += __shfl_xor(s3, 32, 64);
    if (half == 0) {
        float dd = dis[wv];
        float4 b = *(const float4*)&bias[4 * l5];
        float r0 = fmaxf(fmaf(dd, s0, b.x), 0.f);
        float r1 = fmaxf(fmaf(dd, s1, b.y), 0.f);
        float r2 = fmaxf(fmaf(dd, s2, b.z), 0.f);
        float r3 = fmaxf(fmaf(dd, s3, b.w), 0.f);
        uint2 pk;
        pk.x = pack2h(r0, r1);
        pk.y = pack2h(r2, r3);
        *(uint2*)&out[(size_t)wv * FEAT + 4 * l5] = pk;
    }
}

// ---------------- layer-2 prop fused with head projection (fp8 t), range [off,lim) ----------------
// z[i] = dis[i] * (relu(dis[i]*((A+I)@t)[i] + b1) @ Wc)
__global__ __launch_bounds__(256) void prop_zk_kernel(const int* __restrict__ rp,
                                                      const unsigned* __restrict__ cv,
                                                      const float* __restrict__ dis,
                                                      const unsigned char* __restrict__ t8,
                                                      const float* __restrict__ bias,
                                                      const float* __restrict__ Wc,
                                                      float* __restrict__ z,
                                                      int off, int lim) {
    int wv = off + ((blockIdx.x * blockDim.x + threadIdx.x) >> 6);
    int lane = threadIdx.x & 63;
    if (wv >= lim) return;
    int half = lane >> 5, l5 = lane & 31;
    int beg = rp[wv], end = rp[wv + 1];
    const unsigned char* tb = t8 + 4 * l5;
    f32x2 aL[4], aH[4];
#pragma unroll
    for (int j = 0; j < 4; ++j) { aL[j] = (f32x2){0.f, 0.f}; aH[j] = (f32x2){0.f, 0.f}; }
    int deg = end - beg;
    int nfull = deg & ~15;
    int p = beg;
    for (; p < beg + nfull; p += 16) {
#pragma unroll
        for (int jj = 0; jj < 8; ++jj) {
            unsigned e = cv[p + 2 * jj + half];
            unsigned v = *(const unsigned*)(tb + ((size_t)(e & 0x1FFFF) << 7));
            float w = __half2float(__ushort_as_half((unsigned short)(e >> 17)));
            f32x2 w2 = {w, w};
            f32x2 lo = __builtin_amdgcn_cvt_pk_f32_fp8((int)v, false);
            f32x2 hi = __builtin_amdgcn_cvt_pk_f32_fp8((int)v, true);
            aL[jj & 3] = lo * w2 + aL[jj & 3];
            aH[jj & 3] = hi * w2 + aH[jj & 3];
        }
    }
    if (p < end) {
        int last = end - 1;
#pragma unroll
        for (int jj = 0; jj < 8; ++jj) {
            int idx = p + 2 * jj + half;
            unsigned e = cv[min(idx, last)];
            unsigned v = *(const unsigned*)(tb + ((size_t)(e & 0x1FFFF) << 7));
            float w = __half2float(__ushort_as_half((unsigned short)(e >> 17)));
            w = (idx < end) ? w : 0.f;
            f32x2 w2 = {w, w};
            f32x2 lo = __builtin_amdgcn_cvt_pk_f32_fp8((int)v, false);
            f32x2 hi = __builtin_amdgcn_cvt_pk_f32_fp8((int)v, true);
            aL[jj & 3] = lo * w2 + aL[jj & 3];
            aH[jj & 3] = hi * w2 + aH[jj & 3];
        }
    }
    f32x2 sL = (aL[0] + aL[1]) + (aL[2] + aL[3]);
    f32x2 sH = (aH[0] + aH[1]) + (aH[2] + aH[3]);
    float s0 = sL[0], s1 = sL[1], s2 = sH[0], s3 = sH[1];
    s0 += __shfl_xor(s0, 32, 64);
    s1 += __shfl_xor(s1, 32, 64);
    s2 += __shfl_xor(s2, 32, 64);
    s3 += __shfl_xor(s3, 32, 64);
    float dd = dis[wv];
    float4 b = *(const float4*)&bias[4 * l5];
    float h0 = fmaxf(fmaf(dd, s0, b.x), 0.f);
    float h1 = fmaxf(fmaf(dd, s1, b.y), 0.f);
    float h2 = fmaxf(fmaf(dd, s2, b.z), 0.f);
    float h3 = fmaxf(fmaf(dd, s3, b.w), 0.f);
    float4 w0 = *(const float4*)&Wc[16 * l5];
    float4 w1 = *(const float4*)&Wc[16 * l5 + 4];
    float4 w2 = *(const float4*)&Wc[16 * l5 + 8];
    float4 w3 = *(const float4*)&Wc[16 * l5 + 12];
    float4 par;
    par.x = fmaf(h0, w0.x, fmaf(h1, w1.x, fmaf(h2, w2.x, h3 * w3.x)));
    par.y = fmaf(h0, w0.y, fmaf(h1, w1.y, fmaf(h2, w2.y, h3 * w3.y)));
    par.z = fmaf(h0, w0.z, fmaf(h1, w1.z, fmaf(h2, w2.z, h3 * w3.z)));
    par.w = fmaf(h0, w0.w, fmaf(h1, w1.w, fmaf(h2, w2.w, h3 * w3.w)));
#pragma unroll
    for (int mask = 1; mask < 32; mask <<= 1) {
        par.x += __shfl_xor(par.x, mask, 64);
        par.y += __shfl_xor(par.y, mask, 64);
        par.z += __shfl_xor(par.z, mask, 64);
        par.w += __shfl_xor(par.w, mask, 64);
    }
    if (lane == 0) {
        par.x *= dd; par.y *= dd; par.z *= dd; par.w *= dd;   // outer dis for layer-3 prop
        *(float4*)&z[(size_t)wv * 4] = par;
    }
}

// ---------------- CSR propagate, 4 feats: thread/node, 4 edges in flight ----------------
__global__ __launch_bounds__(256) void prop4_kernel(const int* __restrict__ rp,
                                                    const unsigned* __restrict__ cv,
                                                    const float* __restrict__ dis,
                                                    const float* __restrict__ z,
                                                    float* __restrict__ z2, int n) {
    int i = blockIdx.x * blockDim.x + threadIdx.x;
    if (i >= n) return;
    int beg = rp[i], end = rp[i + 1], last = end - 1;
    float4 a[4];
#pragma unroll
    for (int j = 0; j < 4; ++j) a[j] = (float4){0.f, 0.f, 0.f, 0.f};
    for (int p = beg; p < end; p += 4) {
#pragma unroll
        for (int j = 0; j < 4; ++j) {
            int idx = p + j;
            unsigned e = cv[min(idx, last)];
            float wq = __half2float(__ushort_as_half((unsigned short)(e >> 17)));
            wq = (idx < end) ? wq : 0.f;
            float4 v = *(const float4*)&z[(size_t)(e & 0x1FFFF) * 4];
            a[j].x = fmaf(v.x, wq, a[j].x); a[j].y = fmaf(v.y, wq, a[j].y);
            a[j].z = fmaf(v.z, wq, a[j].z); a[j].w = fmaf(v.w, wq, a[j].w);
        }
    }
    float dd = dis[i];
    float4 r;
    r.x = dd * ((a[0].x + a[1].x) + (a[2].x + a[3].x));
    r.y = dd * ((a[0].y + a[1].y) + (a[2].y + a[3].y));
    r.z = dd * ((a[0].z + a[1].z) + (a[2].z + a[3].z));
    r.w = dd * ((a[0].w + a[1].w) + (a[2].w + a[3].w));
    *(float4*)&z2[(size_t)i * 4] = r;
}

// ---------------- segment mean-pool on 4 feats + bias -> out[G x 4] ----------------
__global__ __launch_bounds__(256) void pool4_kernel(const float* __restrict__ z2,
                                                    const int* __restrict__ gstart,
                                                    const float* __restrict__ bc,
                                                    float* __restrict__ out, int G_) {
    __shared__ float sd[256];
    int g = blockIdx.x;
    int k = threadIdx.x & 3;
    int sub = threadIdx.x >> 2;
    int beg = gstart[g], end = gstart[g + 1];
    float s = 0.f;
    for (int i = beg + sub; i < end; i += 64) s += z2[(size_t)i * 4 + k];
    sd[threadIdx.x] = s;
    __syncthreads();
    for (int off = 32; off > 0; off >>= 1) {
        if (sub < off) sd[threadIdx.x] += sd[threadIdx.x + off * 4];
        __syncthreads();
    }
    if (sub == 0) {
        int c = end - beg;
        out[g * 4 + k] = sd[k] / (float)max(c, 1) + bc[k];
    }
}

extern "C" void kernel_launch(void* const* d_in, const int* in_sizes, int n_in,
                              void* d_out, int out_size, void* d_ws, size_t ws_size,
                              hipStream_t stream) {
    const float* x    = (const float*)d_in[0];
    const int*   ei   = (const int*)d_in[1];
    const float* eatt = (const float*)d_in[2];
    const int*   batch= (const int*)d_in[3];
    const float* W0   = (const float*)d_in[4];
    const float* b0   = (const float*)d_in[5];
    const float* W1   = (const float*)d_in[6];
    const float* b1   = (const float*)d_in[7];
    const float* W2   = (const float*)d_in[8];
    const float* b2   = (const float*)d_in[9];
    const float* Wp   = (const float*)d_in[10];
    const float* bp   = (const float*)d_in[11];
    float* out = (float*)d_out;

    const int Nn = in_sizes[0] / FEAT;        // 100000
    const int E_ = in_sizes[2];               // 1600000
    const int G_ = out_size / 4;              // 500
    const int NNZ = E_ + Nn;
    const int NB = ((Nn - 1) >> BSH) + 1;     // 391 buckets

    const int* e_src = ei;
    const int* e_dst = ei + E_;

    // ---- workspace layout ----
    char* ws = (char*)d_ws;
    size_t off = 0;
    auto alloc = [&](size_t bytes) { void* p = ws + off; off = (off + bytes + 255) & ~(size_t)255; return p; };
    float* dis     = (float*)alloc((size_t)Nn * 4);
    int*   rp      = (int*)  alloc((size_t)(Nn + 1) * 4);
    int*   gcnt    = (int*)  alloc((size_t)NB * 4);
    unsigned* cv   = (unsigned*)alloc((size_t)NNZ * 4);
    unsigned short* bufA = (unsigned short*)alloc((size_t)NB * BCAP * 8);  // h1 f16; aliases bins (25.6 MB)
    unsigned char* bufB8 = (unsigned char*)alloc((size_t)Nn * FEAT);       // t1/t2 fp8 (12.8 MB)
    int*   gstart  = (int*)  alloc((size_t)(G_ + 1) * 4);
    float* z       = (float*)alloc((size_t)Nn * 4 * 4);
    float* z2      = (float*)alloc((size_t)Nn * 4 * 4);
    float* Wc      = (float*)alloc(512 * 4);
    float* bc      = (float*)alloc(4 * 4);
    _Float16* Wt0  = (_Float16*)alloc(128 * 128 * 2);
    _Float16* Wt1  = (_Float16*)alloc(128 * 128 * 2);
    int2*  bins    = (int2*)bufA;   // dead before prop1 writes bufA
    (void)ws_size;

    const int T = 256;
    auto cdiv = [](int a, int b) { return (a + b - 1) / b; };
    const int half1 = (Nn + 1) / 2;

    // merged tiny preps (Wt0, Wt1, Wc/bc, gcnt zero, gstart)
    prep_kernel<<<129 + cdiv(Nn, T), T, 0, stream>>>(W0, W1, W2, Wp, b2, bp, batch,
                                                     Wt0, Wt1, Wc, bc, gstart, gcnt,
                                                     Nn, G_, NB);

    // CSR build: bin (LDS-staged) -> fused build (LDS-staged coalesced cv)
    bin1_kernel<<<cdiv(E_, 4096), T, 0, stream>>>(e_src, e_dst, eatt, gcnt, bins, E_, NB);
    buildcsr_kernel<<<NB, T, 0, stream>>>(bins, gcnt, rp, dis, cv, Nn);

    // layer 1: bufB8 = fp8(dis .* (x@W0)) via MFMA; bufA = f16(relu(dis .* ((A+I)@bufB8) + b0))
    gemm1_mfma<<<cdiv(Nn, 64), T, 0, stream>>>(x, Wt0, dis, bufB8, Nn);
    prop_kernel<<<cdiv(half1 * 64, T), T, 0, stream>>>(rp, cv, dis, bufB8, b0, bufA, 0, half1);
    prop_kernel<<<cdiv((Nn - half1) * 64, T), T, 0, stream>>>(rp, cv, dis, bufB8, b0, bufA, half1, Nn);

    // layer 2 + head fused: bufB8 = fp8(dis .* (bufA@W1)); z = dis .* (relu(...)@Wc)
    gemm2_mfma<<<cdiv(Nn, 64), T, 0, stream>>>(bufA, Wt1, dis, bufB8, Nn);
    prop_zk_kernel<<<cdiv(half1 * 64, T), T, 0, stream>>>(rp, cv, dis, bufB8, b1, Wc, z, 0, half1);
    prop_zk_kernel<<<cdiv((Nn - half1) * 64, T), T, 0, stream>>>(rp, cv, dis, bufB8, b1, Wc, z, half1, Nn);

    // layer 3 + pool
    prop4_kernel<<<cdiv(Nn, T), T, 0, stream>>>(rp, cv, dis, z, z2, Nn);
    pool4_kernel<<<G_, T, 0, stream>>>(z2, gstart, bc, out, G_);
}

// Round 8
// 354.912 us; speedup vs baseline: 1.0058x; 1.0058x over previous
//
#include <hip/hip_runtime.h>
#include <hip/hip_bf16.h>
#include <hip/hip_fp16.h>

// GCN, dis-folded: A_norm = D^-1/2 (A_w + I) D^-1/2; CSR stores raw w.
// R20: single-variable fix for the GEMMs. R19's pipelined schedule needs ~104
//      live VGPRs but the compiler capped at 64 (default occupancy heuristic)
//      and re-serialized the loads -- MfmaUtil 2.6%, zero load overlap,
//      41 us. __launch_bounds__(256,4) raises the budget to 128 VGPR
//      (4 waves/SIMD, 16 waves/CU), letting the 8-deep A-load + batched
//      B-load pipeline actually materialize. Everything else unchanged.

#define FEAT 128
#define BSH 8                 // bucket shift
#define BCAP 8192             // entries per bucket (mean 4092)

typedef union { int2 i2; long long u; struct { int s; float w; } e; } EdgePair;
typedef union { unsigned u; __half2 h2; } H2U;
typedef _Float16 f16x8 __attribute__((ext_vector_type(8)));
typedef float f32x4 __attribute__((ext_vector_type(4)));
typedef float f32x2 __attribute__((ext_vector_type(2)));

__device__ __forceinline__ unsigned pack2h(float a, float b) {
    return (unsigned)__half_as_ushort(__float2half_rn(a)) |
           ((unsigned)__half_as_ushort(__float2half_rn(b)) << 16);   // RNE both
}

__device__ __forceinline__ unsigned char to_fp8(float v) {
    int pk = __builtin_amdgcn_cvt_pk_fp8_f32(v, v, 0, false);   // RNE, sat
    return (unsigned char)(pk & 0xFF);
}

// ---------------- pass 1: bin edges by dst>>8, LDS-staged coalesced output ----------------
__global__ __launch_bounds__(256) void bin1_kernel(const int* __restrict__ src,
                                                   const int* __restrict__ dst,
                                                   const float* __restrict__ w,
                                                   int* __restrict__ gcnt,
                                                   int2* __restrict__ bins,
                                                   int E_, int NB) {
    __shared__ int lh[392], lofs[392], lbase[392], lcur[392];
    __shared__ unsigned sU[4096];
    __shared__ float    sW[4096];
    __shared__ unsigned short sB[4096];
    const int CHUNK = 4096;
    int base = blockIdx.x * CHUNK;
    int tid = threadIdx.x;
    for (int t = tid; t < NB; t += 256) { lh[t] = 0; lcur[t] = 0; }
    __syncthreads();
    int ds[16];
#pragma unroll
    for (int j = 0; j < 16; ++j) {
        int e = base + j * 256 + tid;
        ds[j] = (e < E_) ? dst[e] : -1;
        if (ds[j] >= 0) atomicAdd(&lh[ds[j] >> BSH], 1);
    }
    __syncthreads();
    // parallel exclusive prefix: thread t sums lh[0..t-1] (loads pipeline)
    for (int t = tid; t < NB; t += 256) {
        int run = 0;
        for (int i = 0; i < t; ++i) run += lh[i];
        lofs[t] = run;
    }
    __syncthreads();
    for (int t = tid; t < NB; t += 256)
        if (lh[t] > 0) lbase[t] = atomicAdd(&gcnt[t], lh[t]);
    __syncthreads();
    // place edges compactly into LDS staging, bucket-sorted
#pragma unroll
    for (int j = 0; j < 16; ++j) {
        int e = base + j * 256 + tid;
        if (ds[j] >= 0) {
            int b = ds[j] >> BSH;
            int r = atomicAdd(&lcur[b], 1);
            int s = lofs[b] + r;
            sU[s] = (unsigned)src[e] | ((unsigned)(ds[j] & 255) << 20);
            sW[s] = w[e];
            sB[s] = (unsigned short)b;
        }
    }
    __syncthreads();
    // linear copy-out: consecutive threads -> consecutive slots of each bucket run
    int total = min(CHUNK, E_ - base);
    for (int s = tid; s < total; s += 256) {
        int b = sB[s];
        int g = lbase[b] + (s - lofs[b]);
        if (g < BCAP) {
            int2 val; val.x = (int)sU[s]; val.y = __float_as_int(sW[s]);
            bins[(size_t)b * BCAP + g] = val;
        }
    }
}

// ---------------- fused CSR build: self-prefix + histogram + scan + rp/dis +
//                  LDS-staged scatter + coalesced copy-out ----------------
// cv entry: (f16bits(w) << 17) | src   (w in [0,1] -> f16 bits <= 0x3C00, 15 bits)
__global__ __launch_bounds__(256) void buildcsr_kernel(const int2* __restrict__ bins,
                                                       const int* __restrict__ gcnt,
                                                       int* __restrict__ rp,
                                                       float* __restrict__ dis,
                                                       unsigned* __restrict__ cv, int n) {
    __shared__ int lh[256];
    __shared__ float wsum[256];
    __shared__ int sc[256];
    __shared__ int lcur[256];
    __shared__ int red[256];
    __shared__ unsigned scv[BCAP + 256];
    int b = blockIdx.x;
    int tid = threadIdx.x;
    int node0 = b << BSH;
    int node = node0 + tid;
    bool valid = node < n;
    lh[tid] = 0;
    wsum[tid] = 1.0f;   // self-loop weight
    // self-computed exclusive prefix over buckets < b (gcnt L2-hot after bin1)
    int part = 0;
    for (int i = tid; i < b; i += 256)
        part += min(gcnt[i], BCAP) + min(256, n - (i << BSH));
    red[tid] = part;
    __syncthreads();
    for (int off = 128; off > 0; off >>= 1) {
        if (tid < off) red[tid] += red[tid + off];
        __syncthreads();
    }
    int base = red[0];
    int m = min(gcnt[b], BCAP);
    int nvalid = min(256, n - node0);
    if (b == (int)gridDim.x - 1 && tid == 0)
        rp[n] = base + m + nvalid;
    const int2* bp = bins + (size_t)b * BCAP;
    for (int i = tid; i < m; i += 256) {
        int2 raw = bp[i];
        unsigned pk = (unsigned)raw.x;
        int dlo = pk >> 20;
        atomicAdd(&lh[dlo], 1);
        atomicAdd(&wsum[dlo], __int_as_float(raw.y));
    }
    __syncthreads();
    int cnt_t = valid ? (lh[tid] + 1) : 0;   // +1 self-loop
    sc[tid] = cnt_t;
    __syncthreads();
    for (int off = 1; off < 256; off <<= 1) {
        int x = (tid >= off) ? sc[tid - off] : 0;
        __syncthreads();
        sc[tid] += x;
        __syncthreads();
    }
    int excl = sc[tid] - cnt_t;
    if (valid) {
        rp[node] = base + excl;
        dis[node] = rsqrtf(fmaxf(wsum[tid], 1e-12f));
    }
    lcur[tid] = excl;                        // LOCAL positions for staging
    __syncthreads();
    for (int i = tid; i < m; i += 256) {
        int2 raw = bp[i];                    // second read: L2-hot
        unsigned pk = (unsigned)raw.x;
        int dlo = pk >> 20;
        int pos = atomicAdd(&lcur[dlo], 1);
        unsigned hw = (unsigned)__half_as_ushort(__float2half_rn(__int_as_float(raw.y)));
        scv[pos] = (hw << 17) | (pk & 0x1FFFF);
    }
    __syncthreads();
    if (valid) {                             // self-loop entry, w = 1 -> f16 0x3C00
        int pos = atomicAdd(&lcur[tid], 1);
        scv[pos] = (0x3C00u << 17) | (unsigned)node;
    }
    __syncthreads();
    // contiguous coalesced copy-out of the whole bucket range
    int total = m + nvalid;
    for (int s = tid; s < total; s += 256)
        cv[base + s] = scv[s];
}

// ---------------- merged tiny preps ----------------
// blocks [0,64): Wt0; [64,128): Wt1; 128: Wc+bc+gcnt-zero; [129, 129+nbg): gbound
__global__ __launch_bounds__(256) void prep_kernel(const float* __restrict__ W0,
                                                   const float* __restrict__ W1,
                                                   const float* __restrict__ W2,
                                                   const float* __restrict__ Wp,
                                                   const float* __restrict__ b2,
                                                   const float* __restrict__ bp,
                                                   const int* __restrict__ batch,
                                                   _Float16* __restrict__ Wt0,
                                                   _Float16* __restrict__ Wt1,
                                                   float* __restrict__ Wc,
                                                   float* __restrict__ bc,
                                                   int* __restrict__ gstart,
                                                   int* __restrict__ gcnt,
                                                   int n, int G_, int NB) {
    int blk = blockIdx.x;
    if (blk < 64) {
        int tid = blk * 256 + threadIdx.x;
        int nn = tid >> 7, k = tid & 127;
        Wt0[nn * 128 + k] = (_Float16)W0[k * 128 + nn];
    } else if (blk < 128) {
        int tid = (blk - 64) * 256 + threadIdx.x;
        int nn = tid >> 7, k = tid & 127;
        Wt1[nn * 128 + k] = (_Float16)W1[k * 128 + nn];
    } else if (blk == 128) {
        for (int tid = threadIdx.x; tid < 512; tid += 256) {
            int c = tid >> 2, k = tid & 3;
            float s = 0.f;
            for (int j = 0; j < 200; ++j) s = fmaf(W2[c * 200 + j], Wp[j * 4 + k], s);
            Wc[tid] = s;
        }
        if (threadIdx.x < 4) {
            float s = bp[threadIdx.x];
            for (int j = 0; j < 200; ++j) s = fmaf(b2[j], Wp[j * 4 + threadIdx.x], s);
            bc[threadIdx.x] = s;
        }
        for (int i = threadIdx.x; i < NB; i += 256) gcnt[i] = 0;
    } else {
        int i = (blk - 129) * 256 + threadIdx.x;
        if (i >= n) return;
        int b = batch[i];
        int prev = (i == 0) ? -1 : batch[i - 1];
        for (int g = prev + 1; g <= b; ++g) gstart[g] = i;
        if (i == n - 1) {
            for (int g = b + 1; g <= G_; ++g) gstart[g] = n;
        }
    }
}

// ---------------- MFMA GEMM: C_fp8[M x 128] = rowscale .* (A @ W), Wt[n][k] f16 ----------------
// Pipelined: all 8 A-loads issued before use; B loaded in per-t batches of 4
// (t+1 batch overlaps t's MFMAs). __launch_bounds__(256,4): 128-VGPR budget so
// the ~104-reg schedule fits without spill/serialization (R19 was capped at 64).
__global__ __launch_bounds__(256, 4) void gemm1_mfma(const float* __restrict__ A,
                                                     const _Float16* __restrict__ Wt,
                                                     const float* __restrict__ rowscale,
                                                     unsigned char* __restrict__ C, int M) {
    int wid = threadIdx.x >> 6, lane = threadIdx.x & 63;
    int quad = lane >> 4, l16 = lane & 15;
    int row0 = blockIdx.x * 64 + wid * 16;
    int arow = row0 + l16; if (arow >= M) arow = M - 1;   // clamp: pollutes only discarded D rows
    const float* abase = A + (size_t)arow * 128 + quad * 8;
    float4 a0[4], a1[4];
#pragma unroll
    for (int kc = 0; kc < 4; ++kc) {            // 8 independent loads in flight
        a0[kc] = *(const float4*)(abase + kc * 32);
        a1[kc] = *(const float4*)(abase + kc * 32 + 4);
    }
    f16x8 af[4];
#pragma unroll
    for (int kc = 0; kc < 4; ++kc)
        af[kc] = (f16x8){ (_Float16)a0[kc].x, (_Float16)a0[kc].y, (_Float16)a0[kc].z, (_Float16)a0[kc].w,
                          (_Float16)a1[kc].x, (_Float16)a1[kc].y, (_Float16)a1[kc].z, (_Float16)a1[kc].w };
    f32x4 acc[8];
#pragma unroll
    for (int t = 0; t < 8; ++t) acc[t] = (f32x4){0.f, 0.f, 0.f, 0.f};
    const _Float16* wbase = Wt + (size_t)l16 * 128 + quad * 8;
#pragma unroll
    for (int t = 0; t < 8; ++t) {
        f16x8 bf[4];
#pragma unroll
        for (int kc = 0; kc < 4; ++kc)
            bf[kc] = *(const f16x8*)(wbase + (size_t)t * 16 * 128 + kc * 32);
#pragma unroll
        for (int kc = 0; kc < 4; ++kc)
            acc[t] = __builtin_amdgcn_mfma_f32_16x16x32_f16(af[kc], bf[kc], acc[t], 0, 0, 0);
    }
    int orow0 = row0 + quad * 4;
#pragma unroll
    for (int r = 0; r < 4; ++r) {
        int orow = orow0 + r;
        if (orow < M) {
            float sc = rowscale[orow];
#pragma unroll
            for (int t = 0; t < 8; ++t)
                C[(size_t)orow * 128 + t * 16 + l16] = to_fp8(acc[t][r] * sc);
        }
    }
}

__global__ __launch_bounds__(256, 4) void gemm2_mfma(const unsigned short* __restrict__ A,
                                                     const _Float16* __restrict__ Wt,
                                                     const float* __restrict__ rowscale,
                                                     unsigned char* __restrict__ C, int M) {
    int wid = threadIdx.x >> 6, lane = threadIdx.x & 63;
    int quad = lane >> 4, l16 = lane & 15;
    int row0 = blockIdx.x * 64 + wid * 16;
    int arow = row0 + l16; if (arow >= M) arow = M - 1;
    const _Float16* abase = (const _Float16*)A + (size_t)arow * 128 + quad * 8;
    f16x8 af[4];
#pragma unroll
    for (int kc = 0; kc < 4; ++kc)              // 4 independent loads in flight
        af[kc] = *(const f16x8*)(abase + kc * 32);
    f32x4 acc[8];
#pragma unroll
    for (int t = 0; t < 8; ++t) acc[t] = (f32x4){0.f, 0.f, 0.f, 0.f};
    const _Float16* wbase = Wt + (size_t)l16 * 128 + quad * 8;
#pragma unroll
    for (int t = 0; t < 8; ++t) {
        f16x8 bf[4];
#pragma unroll
        for (int kc = 0; kc < 4; ++kc)
            bf[kc] = *(const f16x8*)(wbase + (size_t)t * 16 * 128 + kc * 32);
#pragma unroll
        for (int kc = 0; kc < 4; ++kc)
            acc[t] = __builtin_amdgcn_mfma_f32_16x16x32_f16(af[kc], bf[kc], acc[t], 0, 0, 0);
    }
    int orow0 = row0 + quad * 4;
#pragma unroll
    for (int r = 0; r < 4; ++r) {
        int orow = orow0 + r;
        if (orow < M) {
            float sc = rowscale[orow];
#pragma unroll
            for (int t = 0; t < 8; ++t)
                C[(size_t)orow * 128 + t * 16 + l16] = to_fp8(acc[t][r] * sc);
        }
    }
}

// ---------------- CSR propagate, 128 fp8 feats (layer 1), node range [off,lim) ----------------
// wave/node; half-wave per edge, 32 lanes x 4 fp8. Full 16-edge rounds carry
// no clamp/cndmask; only the tail round does. f32x2 packed accumulate.
__global__ __launch_bounds__(256) void prop_kernel(const int* __restrict__ rp,
                                                   const unsigned* __restrict__ cv,
                                                   const float* __restrict__ dis,
                                                   const unsigned char* __restrict__ t8,
                                                   const float* __restrict__ bias,
                                                   unsigned short* __restrict__ out,
                                                   int off, int lim) {
    int wv = off + ((blockIdx.x * blockDim.x + threadIdx.x) >> 6);
    int lane = threadIdx.x & 63;
    if (wv >= lim) return;
    int half = lane >> 5, l5 = lane & 31;
    int beg = rp[wv], end = rp[wv + 1];
    const unsigned char* tb = t8 + 4 * l5;
    f32x2 aL[4], aH[4];
#pragma unroll
    for (int j = 0; j < 4; ++j) { aL[j] = (f32x2){0.f, 0.f}; aH[j] = (f32x2){0.f, 0.f}; }
    int deg = end - beg;
    int nfull = deg & ~15;
    int p = beg;
    for (; p < beg + nfull; p += 16) {
#pragma unroll
        for (int jj = 0; jj < 8; ++jj) {
            unsigned e = cv[p + 2 * jj + half];
            unsigned v = *(const unsigned*)(tb + ((size_t)(e & 0x1FFFF) << 7));
            float w = __half2float(__ushort_as_half((unsigned short)(e >> 17)));
            f32x2 w2 = {w, w};
            f32x2 lo = __builtin_amdgcn_cvt_pk_f32_fp8((int)v, false);
            f32x2 hi = __builtin_amdgcn_cvt_pk_f32_fp8((int)v, true);
            aL[jj & 3] = lo * w2 + aL[jj & 3];
            aH[jj & 3] = hi * w2 + aH[jj & 3];
        }
    }
    if (p < end) {
        int last = end - 1;
#pragma unroll
        for (int jj = 0; jj < 8; ++jj) {
            int idx = p + 2 * jj + half;
            unsigned e = cv[min(idx, last)];
            unsigned v = *(const unsigned*)(tb + ((size_t)(e & 0x1FFFF) << 7));
            float w = __half2float(__ushort_as_half((unsigned short)(e >> 17)));
            w = (idx < end) ? w : 0.f;
            f32x2 w2 = {w, w};
            f32x2 lo = __builtin_amdgcn_cvt_pk_f32_fp8((int)v, false);
            f32x2 hi = __builtin_amdgcn_cvt_pk_f32_fp8((int)v, true);
            aL[jj & 3] = lo * w2 + aL[jj & 3];
            aH[jj & 3] = hi * w2 + aH[jj & 3];
        }
    }
    f32x2 sL = (aL[0] + aL[1]) + (aL[2] + aL[3]);
    f32x2 sH = (aH[0] + aH[1]) + (aH[2] + aH[3]);
    float s0 = sL[0], s1 = sL[1], s2 = sH[0], s3 = sH[1];
    s0 += __shfl_xor(s0, 32, 64);
    s1 += __shfl_xor(s1, 32, 64);
    s2 += __shfl_xor(s2, 32, 64);
    s3 += __shfl_xor(s3, 32, 64);
    if (half == 0) {
        float dd = dis[wv];
        float4 b = *(const float4*)&bias[4 * l5];
        float r0 = fmaxf(fmaf(dd, s0, b.x), 0.f);
        float r1 = fmaxf(fmaf(dd, s1, b.y), 0.f);
        float r2 = fmaxf(fmaf(dd, s2, b.z), 0.f);
        float r3 = fmaxf(fmaf(dd, s3, b.w), 0.f);
        uint2 pk;
        pk.x = pack2h(r0, r1);
        pk.y = pack2h(r2, r3);
        *(uint2*)&out[(size_t)wv * FEAT + 4 * l5] = pk;
    }
}

// ---------------- layer-2 prop fused with head projection (fp8 t), range [off,lim) ----------------
// z[i] = dis[i] * (relu(dis[i]*((A+I)@t)[i] + b1) @ Wc)
__global__ __launch_bounds__(256) void prop_zk_kernel(const int* __restrict__ rp,
                                                      const unsigned* __restrict__ cv,
                                                      const float* __restrict__ dis,
                                                      const unsigned char* __restrict__ t8,
                                                      const float* __restrict__ bias,
                                                      const float* __restrict__ Wc,
                                                      float* __restrict__ z,
                                                      int off, int lim) {
    int wv = off + ((blockIdx.x * blockDim.x + threadIdx.x) >> 6);
    int lane = threadIdx.x & 63;
    if (wv >= lim) return;
    int half = lane >> 5, l5 = lane & 31;
    int beg = rp[wv], end = rp[wv + 1];
    const unsigned char* tb = t8 + 4 * l5;
    f32x2 aL[4], aH[4];
#pragma unroll
    for (int j = 0; j < 4; ++j) { aL[j] = (f32x2){0.f, 0.f}; aH[j] = (f32x2){0.f, 0.f}; }
    int deg = end - beg;
    int nfull = deg & ~15;
    int p = beg;
    for (; p < beg + nfull; p += 16) {
#pragma unroll
        for (int jj = 0; jj < 8; ++jj) {
            unsigned e = cv[p + 2 * jj + half];
            unsigned v = *(const unsigned*)(tb + ((size_t)(e & 0x1FFFF) << 7));
            float w = __half2float(__ushort_as_half((unsigned short)(e >> 17)));
            f32x2 w2 = {w, w};
            f32x2 lo = __builtin_amdgcn_cvt_pk_f32_fp8((int)v, false);
            f32x2 hi = __builtin_amdgcn_cvt_pk_f32_fp8((int)v, true);
            aL[jj & 3] = lo * w2 + aL[jj & 3];
            aH[jj & 3] = hi * w2 + aH[jj & 3];
        }
    }
    if (p < end) {
        int last = end - 1;
#pragma unroll
        for (int jj = 0; jj < 8; ++jj) {
            int idx = p + 2 * jj + half;
            unsigned e = cv[min(idx, last)];
            unsigned v = *(const unsigned*)(tb + ((size_t)(e & 0x1FFFF) << 7));
            float w = __half2float(__ushort_as_half((unsigned short)(e >> 17)));
            w = (idx < end) ? w : 0.f;
            f32x2 w2 = {w, w};
            f32x2 lo = __builtin_amdgcn_cvt_pk_f32_fp8((int)v, false);
            f32x2 hi = __builtin_amdgcn_cvt_pk_f32_fp8((int)v, true);
            aL[jj & 3] = lo * w2 + aL[jj & 3];
            aH[jj & 3] = hi * w2 + aH[jj & 3];
        }
    }
    f32x2 sL = (aL[0] + aL[1]) + (aL[2] + aL[3]);
    f32x2 sH = (aH[0] + aH[1]) + (aH[2] + aH[3]);
    float s0 = sL[0], s1 = sL[1], s2 = sH[0], s3 = sH[1];
    s0 += __shfl_xor(s0, 32, 64);
    s1 += __shfl_xor(s1, 32, 64);
    s2 += __shfl_xor(s2, 32, 64);
    s3 += __shfl_xor(s3, 32, 64);
    float dd = dis[wv];
    float4 b = *(const float4*)&bias[4 * l5];
    float h0 = fmaxf(fmaf(dd, s0, b.x), 0.f);
    float h1 = fmaxf(fmaf(dd, s1, b.y), 0.f);
    float h2 = fmaxf(fmaf(dd, s2, b.z), 0.f);
    float h3 = fmaxf(fmaf(dd, s3, b.w), 0.f);
    float4 w0 = *(const float4*)&Wc[16 * l5];
    float4 w1 = *(const float4*)&Wc[16 * l5 + 4];
    float4 w2 = *(const float4*)&Wc[16 * l5 + 8];
    float4 w3 = *(const float4*)&Wc[16 * l5 + 12];
    float4 par;
    par.x = fmaf(h0, w0.x, fmaf(h1, w1.x, fmaf(h2, w2.x, h3 * w3.x)));
    par.y = fmaf(h0, w0.y, fmaf(h1, w1.y, fmaf(h2, w2.y, h3 * w3.y)));
    par.z = fmaf(h0, w0.z, fmaf(h1, w1.z, fmaf(h2, w2.z, h3 * w3.z)));
    par.w = fmaf(h0, w0.w, fmaf(h1, w1.w, fmaf(h2, w2.w, h3 * w3.w)));
#pragma unroll
    for (int mask = 1; mask < 32; mask <<= 1) {
        par.x += __shfl_xor(par.x, mask, 64);
        par.y += __shfl_xor(par.y, mask, 64);
        par.z += __shfl_xor(par.z, mask, 64);
        par.w += __shfl_xor(par.w, mask, 64);
    }
    if (lane == 0) {
        par.x *= dd; par.y *= dd; par.z *= dd; par.w *= dd;   // outer dis for layer-3 prop
        *(float4*)&z[(size_t)wv * 4] = par;
    }
}

// ---------------- CSR propagate, 4 feats: thread/node, 4 edges in flight ----------------
__global__ __launch_bounds__(256) void prop4_kernel(const int* __restrict__ rp,
                                                    const unsigned* __restrict__ cv,
                                                    const float* __restrict__ dis,
                                                    const float* __restrict__ z,
                                                    float* __restrict__ z2, int n) {
    int i = blockIdx.x * blockDim.x + threadIdx.x;
    if (i >= n) return;
    int beg = rp[i], end = rp[i + 1], last = end - 1;
    float4 a[4];
#pragma unroll
    for (int j = 0; j < 4; ++j) a[j] = (float4){0.f, 0.f, 0.f, 0.f};
    for (int p = beg; p < end; p += 4) {
#pragma unroll
        for (int j = 0; j < 4; ++j) {
            int idx = p + j;
            unsigned e = cv[min(idx, last)];
            float wq = __half2float(__ushort_as_half((unsigned short)(e >> 17)));
            wq = (idx < end) ? wq : 0.f;
            float4 v = *(const float4*)&z[(size_t)(e & 0x1FFFF) * 4];
            a[j].x = fmaf(v.x, wq, a[j].x); a[j].y = fmaf(v.y, wq, a[j].y);
            a[j].z = fmaf(v.z, wq, a[j].z); a[j].w = fmaf(v.w, wq, a[j].w);
        }
    }
    float dd = dis[i];
    float4 r;
    r.x = dd * ((a[0].x + a[1].x) + (a[2].x + a[3].x));
    r.y = dd * ((a[0].y + a[1].y) + (a[2].y + a[3].y));
    r.z = dd * ((a[0].z + a[1].z) + (a[2].z + a[3].z));
    r.w = dd * ((a[0].w + a[1].w) + (a[2].w + a[3].w));
    *(float4*)&z2[(size_t)i * 4] = r;
}

// ---------------- segment mean-pool on 4 feats + bias -> out[G x 4] ----------------
__global__ __launch_bounds__(256) void pool4_kernel(const float* __restrict__ z2,
                                                    const int* __restrict__ gstart,
                                                    const float* __restrict__ bc,
                                                    float* __restrict__ out, int G_) {
    __shared__ float sd[256];
    int g = blockIdx.x;
    int k = threadIdx.x & 3;
    int sub = threadIdx.x >> 2;
    int beg = gstart[g], end = gstart[g + 1];
    float s = 0.f;
    for (int i = beg + sub; i < end; i += 64) s += z2[(size_t)i * 4 + k];
    sd[threadIdx.x] = s;
    __syncthreads();
    for (int off = 32; off > 0; off >>= 1) {
        if (sub < off) sd[threadIdx.x] += sd[threadIdx.x + off * 4];
        __syncthreads();
    }
    if (sub == 0) {
        int c = end - beg;
        out[g * 4 + k] = sd[k] / (float)max(c, 1) + bc[k];
    }
}

extern "C" void kernel_launch(void* const* d_in, const int* in_sizes, int n_in,
                              void* d_out, int out_size, void* d_ws, size_t ws_size,
                              hipStream_t stream) {
    const float* x    = (const float*)d_in[0];
    const int*   ei   = (const int*)d_in[1];
    const float* eatt = (const float*)d_in[2];
    const int*   batch= (const int*)d_in[3];
    const float* W0   = (const float*)d_in[4];
    const float* b0   = (const float*)d_in[5];
    const float* W1   = (const float*)d_in[6];
    const float* b1   = (const float*)d_in[7];
    const float* W2   = (const float*)d_in[8];
    const float* b2   = (const float*)d_in[9];
    const float* Wp   = (const float*)d_in[10];
    const float* bp   = (const float*)d_in[11];
    float* out = (float*)d_out;

    const int Nn = in_sizes[0] / FEAT;        // 100000
    const int E_ = in_sizes[2];               // 1600000
    const int G_ = out_size / 4;              // 500
    const int NNZ = E_ + Nn;
    const int NB = ((Nn - 1) >> BSH) + 1;     // 391 buckets

    const int* e_src = ei;
    const int* e_dst = ei + E_;

    // ---- workspace layout ----
    char* ws = (char*)d_ws;
    size_t off = 0;
    auto alloc = [&](size_t bytes) { void* p = ws + off; off = (off + bytes + 255) & ~(size_t)255; return p; };
    float* dis     = (float*)alloc((size_t)Nn * 4);
    int*   rp      = (int*)  alloc((size_t)(Nn + 1) * 4);
    int*   gcnt    = (int*)  alloc((size_t)NB * 4);
    unsigned* cv   = (unsigned*)alloc((size_t)NNZ * 4);
    unsigned short* bufA = (unsigned short*)alloc((size_t)NB * BCAP * 8);  // h1 f16; aliases bins (25.6 MB)
    unsigned char* bufB8 = (unsigned char*)alloc((size_t)Nn * FEAT);       // t1/t2 fp8 (12.8 MB)
    int*   gstart  = (int*)  alloc((size_t)(G_ + 1) * 4);
    float* z       = (float*)alloc((size_t)Nn * 4 * 4);
    float* z2      = (float*)alloc((size_t)Nn * 4 * 4);
    float* Wc      = (float*)alloc(512 * 4);
    float* bc      = (float*)alloc(4 * 4);
    _Float16* Wt0  = (_Float16*)alloc(128 * 128 * 2);
    _Float16* Wt1  = (_Float16*)alloc(128 * 128 * 2);
    int2*  bins    = (int2*)bufA;   // dead before prop1 writes bufA
    (void)ws_size;

    const int T = 256;
    auto cdiv = [](int a, int b) { return (a + b - 1) / b; };
    const int half1 = (Nn + 1) / 2;

    // merged tiny preps (Wt0, Wt1, Wc/bc, gcnt zero, gstart)
    prep_kernel<<<129 + cdiv(Nn, T), T, 0, stream>>>(W0, W1, W2, Wp, b2, bp, batch,
                                                     Wt0, Wt1, Wc, bc, gstart, gcnt,
                                                     Nn, G_, NB);

    // CSR build: bin (LDS-staged) -> fused build (LDS-staged coalesced cv)
    bin1_kernel<<<cdiv(E_, 4096), T, 0, stream>>>(e_src, e_dst, eatt, gcnt, bins, E_, NB);
    buildcsr_kernel<<<NB, T, 0, stream>>>(bins, gcnt, rp, dis, cv, Nn);

    // layer 1: bufB8 = fp8(dis .* (x@W0)) via MFMA; bufA = f16(relu(dis .* ((A+I)@bufB8) + b0))
    gemm1_mfma<<<cdiv(Nn, 64), T, 0, stream>>>(x, Wt0, dis, bufB8, Nn);
    prop_kernel<<<cdiv(half1 * 64, T), T, 0, stream>>>(rp, cv, dis, bufB8, b0, bufA, 0, half1);
    prop_kernel<<<cdiv((Nn - half1) * 64, T), T, 0, stream>>>(rp, cv, dis, bufB8, b0, bufA, half1, Nn);

    // layer 2 + head fused: bufB8 = fp8(dis .* (bufA@W1)); z = dis .* (relu(...)@Wc)
    gemm2_mfma<<<cdiv(Nn, 64), T, 0, stream>>>(bufA, Wt1, dis, bufB8, Nn);
    prop_zk_kernel<<<cdiv(half1 * 64, T), T, 0, stream>>>(rp, cv, dis, bufB8, b1, Wc, z, 0, half1);
    prop_zk_kernel<<<cdiv((Nn - half1) * 64, T), T, 0, stream>>>(rp, cv, dis, bufB8, b1, Wc, z, half1, Nn);

    // layer 3 + pool
    prop4_kernel<<<cdiv(Nn, T), T, 0, stream>>>(rp, cv, dis, z, z2, Nn);
    pool4_kernel<<<G_, T, 0, stream>>>(z2, gstart, bc, out, G_);
}

// Round 9
// 349.940 us; speedup vs baseline: 1.0201x; 1.0142x over previous
//
#include <hip/hip_runtime.h>
#include <hip/hip_bf16.h>
#include <hip/hip_fp16.h>

// GCN, dis-folded: A_norm = D^-1/2 (A_w + I) D^-1/2; CSR stores raw w.
// R21: GEMM schedule forced structurally (3 rounds of source-level pipelining
//      were re-serialized by the compiler: VGPR 48/64/52, ~40 us flat).
//      Wt staged in LDS per block (XOR-swizzled (row&7)<<4 -> 2-way instead of
//      16-way ds_read_b128 conflicts); A-loads issued before staging so their
//      latency hides under stage+sync, and the t-loop forces all 8 in flight.
//      Bit-identical FMA order. bin1 CHUNK 4096->1024 (391->1563 blocks; was
//      1.5 blocks/CU). Props/buildcsr/rest unchanged from R20.

#define FEAT 128
#define BSH 8                 // bucket shift
#define BCAP 8192             // entries per bucket (mean 4092)

typedef union { int2 i2; long long u; struct { int s; float w; } e; } EdgePair;
typedef union { unsigned u; __half2 h2; } H2U;
typedef _Float16 f16x8 __attribute__((ext_vector_type(8)));
typedef float f32x4 __attribute__((ext_vector_type(4)));
typedef float f32x2 __attribute__((ext_vector_type(2)));

__device__ __forceinline__ unsigned pack2h(float a, float b) {
    return (unsigned)__half_as_ushort(__float2half_rn(a)) |
           ((unsigned)__half_as_ushort(__float2half_rn(b)) << 16);   // RNE both
}

__device__ __forceinline__ unsigned char to_fp8(float v) {
    int pk = __builtin_amdgcn_cvt_pk_fp8_f32(v, v, 0, false);   // RNE, sat
    return (unsigned char)(pk & 0xFF);
}

// ---------------- pass 1: bin edges by dst>>8, LDS-staged coalesced output ----------------
// CHUNK=1024: 1563 blocks (vs 391) so the binning phase actually fills the GPU.
__global__ __launch_bounds__(256) void bin1_kernel(const int* __restrict__ src,
                                                   const int* __restrict__ dst,
                                                   const float* __restrict__ w,
                                                   int* __restrict__ gcnt,
                                                   int2* __restrict__ bins,
                                                   int E_, int NB) {
    __shared__ int lh[392], lofs[392], lbase[392], lcur[392];
    __shared__ unsigned sU[1024];
    __shared__ float    sW[1024];
    __shared__ unsigned short sB[1024];
    const int CHUNK = 1024;
    int base = blockIdx.x * CHUNK;
    int tid = threadIdx.x;
    for (int t = tid; t < NB; t += 256) { lh[t] = 0; lcur[t] = 0; }
    __syncthreads();
    int ds[4];
#pragma unroll
    for (int j = 0; j < 4; ++j) {
        int e = base + j * 256 + tid;
        ds[j] = (e < E_) ? dst[e] : -1;
        if (ds[j] >= 0) atomicAdd(&lh[ds[j] >> BSH], 1);
    }
    __syncthreads();
    // parallel exclusive prefix: thread t sums lh[0..t-1] (loads pipeline)
    for (int t = tid; t < NB; t += 256) {
        int run = 0;
        for (int i = 0; i < t; ++i) run += lh[i];
        lofs[t] = run;
    }
    __syncthreads();
    for (int t = tid; t < NB; t += 256)
        if (lh[t] > 0) lbase[t] = atomicAdd(&gcnt[t], lh[t]);
    __syncthreads();
    // place edges compactly into LDS staging, bucket-sorted
#pragma unroll
    for (int j = 0; j < 4; ++j) {
        int e = base + j * 256 + tid;
        if (ds[j] >= 0) {
            int b = ds[j] >> BSH;
            int r = atomicAdd(&lcur[b], 1);
            int s = lofs[b] + r;
            sU[s] = (unsigned)src[e] | ((unsigned)(ds[j] & 255) << 20);
            sW[s] = w[e];
            sB[s] = (unsigned short)b;
        }
    }
    __syncthreads();
    // linear copy-out: consecutive threads -> consecutive slots of each bucket run
    int total = min(CHUNK, E_ - base);
    for (int s = tid; s < total; s += 256) {
        int b = sB[s];
        int g = lbase[b] + (s - lofs[b]);
        if (g < BCAP) {
            int2 val; val.x = (int)sU[s]; val.y = __float_as_int(sW[s]);
            bins[(size_t)b * BCAP + g] = val;
        }
    }
}

// ---------------- fused CSR build: self-prefix + histogram + scan + rp/dis +
//                  LDS-staged scatter + coalesced copy-out ----------------
// cv entry: (f16bits(w) << 17) | src   (w in [0,1] -> f16 bits <= 0x3C00, 15 bits)
__global__ __launch_bounds__(256) void buildcsr_kernel(const int2* __restrict__ bins,
                                                       const int* __restrict__ gcnt,
                                                       int* __restrict__ rp,
                                                       float* __restrict__ dis,
                                                       unsigned* __restrict__ cv, int n) {
    __shared__ int lh[256];
    __shared__ float wsum[256];
    __shared__ int sc[256];
    __shared__ int lcur[256];
    __shared__ int red[256];
    __shared__ unsigned scv[BCAP + 256];
    int b = blockIdx.x;
    int tid = threadIdx.x;
    int node0 = b << BSH;
    int node = node0 + tid;
    bool valid = node < n;
    lh[tid] = 0;
    wsum[tid] = 1.0f;   // self-loop weight
    // self-computed exclusive prefix over buckets < b (gcnt L2-hot after bin1)
    int part = 0;
    for (int i = tid; i < b; i += 256)
        part += min(gcnt[i], BCAP) + min(256, n - (i << BSH));
    red[tid] = part;
    __syncthreads();
    for (int off = 128; off > 0; off >>= 1) {
        if (tid < off) red[tid] += red[tid + off];
        __syncthreads();
    }
    int base = red[0];
    int m = min(gcnt[b], BCAP);
    int nvalid = min(256, n - node0);
    if (b == (int)gridDim.x - 1 && tid == 0)
        rp[n] = base + m + nvalid;
    const int2* bp = bins + (size_t)b * BCAP;
    for (int i = tid; i < m; i += 256) {
        int2 raw = bp[i];
        unsigned pk = (unsigned)raw.x;
        int dlo = pk >> 20;
        atomicAdd(&lh[dlo], 1);
        atomicAdd(&wsum[dlo], __int_as_float(raw.y));
    }
    __syncthreads();
    int cnt_t = valid ? (lh[tid] + 1) : 0;   // +1 self-loop
    sc[tid] = cnt_t;
    __syncthreads();
    for (int off = 1; off < 256; off <<= 1) {
        int x = (tid >= off) ? sc[tid - off] : 0;
        __syncthreads();
        sc[tid] += x;
        __syncthreads();
    }
    int excl = sc[tid] - cnt_t;
    if (valid) {
        rp[node] = base + excl;
        dis[node] = rsqrtf(fmaxf(wsum[tid], 1e-12f));
    }
    lcur[tid] = excl;                        // LOCAL positions for staging
    __syncthreads();
    for (int i = tid; i < m; i += 256) {
        int2 raw = bp[i];                    // second read: L2-hot
        unsigned pk = (unsigned)raw.x;
        int dlo = pk >> 20;
        int pos = atomicAdd(&lcur[dlo], 1);
        unsigned hw = (unsigned)__half_as_ushort(__float2half_rn(__int_as_float(raw.y)));
        scv[pos] = (hw << 17) | (pk & 0x1FFFF);
    }
    __syncthreads();
    if (valid) {                             // self-loop entry, w = 1 -> f16 0x3C00
        int pos = atomicAdd(&lcur[tid], 1);
        scv[pos] = (0x3C00u << 17) | (unsigned)node;
    }
    __syncthreads();
    // contiguous coalesced copy-out of the whole bucket range
    int total = m + nvalid;
    for (int s = tid; s < total; s += 256)
        cv[base + s] = scv[s];
}

// ---------------- merged tiny preps ----------------
// blocks [0,64): Wt0; [64,128): Wt1; 128: Wc+bc+gcnt-zero; [129, 129+nbg): gbound
__global__ __launch_bounds__(256) void prep_kernel(const float* __restrict__ W0,
                                                   const float* __restrict__ W1,
                                                   const float* __restrict__ W2,
                                                   const float* __restrict__ Wp,
                                                   const float* __restrict__ b2,
                                                   const float* __restrict__ bp,
                                                   const int* __restrict__ batch,
                                                   _Float16* __restrict__ Wt0,
                                                   _Float16* __restrict__ Wt1,
                                                   float* __restrict__ Wc,
                                                   float* __restrict__ bc,
                                                   int* __restrict__ gstart,
                                                   int* __restrict__ gcnt,
                                                   int n, int G_, int NB) {
    int blk = blockIdx.x;
    if (blk < 64) {
        int tid = blk * 256 + threadIdx.x;
        int nn = tid >> 7, k = tid & 127;
        Wt0[nn * 128 + k] = (_Float16)W0[k * 128 + nn];
    } else if (blk < 128) {
        int tid = (blk - 64) * 256 + threadIdx.x;
        int nn = tid >> 7, k = tid & 127;
        Wt1[nn * 128 + k] = (_Float16)W1[k * 128 + nn];
    } else if (blk == 128) {
        for (int tid = threadIdx.x; tid < 512; tid += 256) {
            int c = tid >> 2, k = tid & 3;
            float s = 0.f;
            for (int j = 0; j < 200; ++j) s = fmaf(W2[c * 200 + j], Wp[j * 4 + k], s);
            Wc[tid] = s;
        }
        if (threadIdx.x < 4) {
            float s = bp[threadIdx.x];
            for (int j = 0; j < 200; ++j) s = fmaf(b2[j], Wp[j * 4 + threadIdx.x], s);
            bc[threadIdx.x] = s;
        }
        for (int i = threadIdx.x; i < NB; i += 256) gcnt[i] = 0;
    } else {
        int i = (blk - 129) * 256 + threadIdx.x;
        if (i >= n) return;
        int b = batch[i];
        int prev = (i == 0) ? -1 : batch[i - 1];
        for (int g = prev + 1; g <= b; ++g) gstart[g] = i;
        if (i == n - 1) {
            for (int g = b + 1; g <= G_; ++g) gstart[g] = n;
        }
    }
}

// ---------------- MFMA GEMM: C_fp8[M x 128] = rowscale .* (A @ W), Wt[n][k] f16 ----------------
// Wt staged in LDS (XOR-swizzled: byte ^= (row&7)<<4 -> strided b128 reads are
// 2-way conflict (free) instead of 16-way). A-loads issued before staging so
// HBM latency hides under stage+sync; first t-iteration needs all af[kc] ->
// all 8 loads forced in flight. Same FMA order -> bit-identical output.
__global__ __launch_bounds__(256, 4) void gemm1_mfma(const float* __restrict__ A,
                                                     const _Float16* __restrict__ Wt,
                                                     const float* __restrict__ rowscale,
                                                     unsigned char* __restrict__ C, int M) {
    __shared__ _Float16 sWt[128 * 128];
    int tid = threadIdx.x;
    int wid = tid >> 6, lane = tid & 63;
    int quad = lane >> 4, l16 = lane & 15;
    int row0 = blockIdx.x * 64 + wid * 16;
    int arow = row0 + l16; if (arow >= M) arow = M - 1;   // clamp: pollutes only discarded D rows
    const float* abase = A + (size_t)arow * 128 + quad * 8;
    float4 a0[4], a1[4];
#pragma unroll
    for (int kc = 0; kc < 4; ++kc) {            // 8 loads issued before staging
        a0[kc] = *(const float4*)(abase + kc * 32);
        a1[kc] = *(const float4*)(abase + kc * 32 + 4);
    }
    {   // stage Wt -> LDS, swizzled
        const char* s = (const char*)Wt;
        char* d = (char*)sWt;
#pragma unroll
        for (int j = 0; j < 8; ++j) {
            int o = (tid + j * 256) * 16;                    // linear byte offset
            int so = o ^ (((o >> 8) & 7) << 4);              // (row&7)<<4
            *(uint4*)(d + so) = *(const uint4*)(s + o);
        }
    }
    __syncthreads();
    f16x8 af[4];
#pragma unroll
    for (int kc = 0; kc < 4; ++kc)
        af[kc] = (f16x8){ (_Float16)a0[kc].x, (_Float16)a0[kc].y, (_Float16)a0[kc].z, (_Float16)a0[kc].w,
                          (_Float16)a1[kc].x, (_Float16)a1[kc].y, (_Float16)a1[kc].z, (_Float16)a1[kc].w };
    f32x4 acc[8];
#pragma unroll
    for (int t = 0; t < 8; ++t) acc[t] = (f32x4){0.f, 0.f, 0.f, 0.f};
    const char* wb = (const char*)sWt;
    int xorv = (l16 & 7) << 4;
#pragma unroll
    for (int t = 0; t < 8; ++t) {
        f16x8 bf[4];
#pragma unroll
        for (int kc = 0; kc < 4; ++kc) {
            int o = (((t * 16 + l16) * 128 + quad * 8 + kc * 32) * 2) ^ xorv;
            bf[kc] = *(const f16x8*)(wb + o);
        }
#pragma unroll
        for (int kc = 0; kc < 4; ++kc)
            acc[t] = __builtin_amdgcn_mfma_f32_16x16x32_f16(af[kc], bf[kc], acc[t], 0, 0, 0);
    }
    int orow0 = row0 + quad * 4;
#pragma unroll
    for (int r = 0; r < 4; ++r) {
        int orow = orow0 + r;
        if (orow < M) {
            float sc = rowscale[orow];
#pragma unroll
            for (int t = 0; t < 8; ++t)
                C[(size_t)orow * 128 + t * 16 + l16] = to_fp8(acc[t][r] * sc);
        }
    }
}

__global__ __launch_bounds__(256, 4) void gemm2_mfma(const unsigned short* __restrict__ A,
                                                     const _Float16* __restrict__ Wt,
                                                     const float* __restrict__ rowscale,
                                                     unsigned char* __restrict__ C, int M) {
    __shared__ _Float16 sWt[128 * 128];
    int tid = threadIdx.x;
    int wid = tid >> 6, lane = tid & 63;
    int quad = lane >> 4, l16 = lane & 15;
    int row0 = blockIdx.x * 64 + wid * 16;
    int arow = row0 + l16; if (arow >= M) arow = M - 1;
    const _Float16* abase = (const _Float16*)A + (size_t)arow * 128 + quad * 8;
    f16x8 af[4];
#pragma unroll
    for (int kc = 0; kc < 4; ++kc)              // 4 loads issued before staging
        af[kc] = *(const f16x8*)(abase + kc * 32);
    {   // stage Wt -> LDS, swizzled
        const char* s = (const char*)Wt;
        char* d = (char*)sWt;
#pragma unroll
        for (int j = 0; j < 8; ++j) {
            int o = (tid + j * 256) * 16;
            int so = o ^ (((o >> 8) & 7) << 4);
            *(uint4*)(d + so) = *(const uint4*)(s + o);
        }
    }
    __syncthreads();
    f32x4 acc[8];
#pragma unroll
    for (int t = 0; t < 8; ++t) acc[t] = (f32x4){0.f, 0.f, 0.f, 0.f};
    const char* wb = (const char*)sWt;
    int xorv = (l16 & 7) << 4;
#pragma unroll
    for (int t = 0; t < 8; ++t) {
        f16x8 bf[4];
#pragma unroll
        for (int kc = 0; kc < 4; ++kc) {
            int o = (((t * 16 + l16) * 128 + quad * 8 + kc * 32) * 2) ^ xorv;
            bf[kc] = *(const f16x8*)(wb + o);
        }
#pragma unroll
        for (int kc = 0; kc < 4; ++kc)
            acc[t] = __builtin_amdgcn_mfma_f32_16x16x32_f16(af[kc], bf[kc], acc[t], 0, 0, 0);
    }
    int orow0 = row0 + quad * 4;
#pragma unroll
    for (int r = 0; r < 4; ++r) {
        int orow = orow0 + r;
        if (orow < M) {
            float sc = rowscale[orow];
#pragma unroll
            for (int t = 0; t < 8; ++t)
                C[(size_t)orow * 128 + t * 16 + l16] = to_fp8(acc[t][r] * sc);
        }
    }
}

// ---------------- CSR propagate, 128 fp8 feats (layer 1), node range [off,lim) ----------------
// wave/node; half-wave per edge, 32 lanes x 4 fp8. Full 16-edge rounds carry
// no clamp/cndmask; only the tail round does. f32x2 packed accumulate.
__global__ __launch_bounds__(256) void prop_kernel(const int* __restrict__ rp,
                                                   const unsigned* __restrict__ cv,
                                                   const float* __restrict__ dis,
                                                   const unsigned char* __restrict__ t8,
                                                   const float* __restrict__ bias,
                                                   unsigned short* __restrict__ out,
                                                   int off, int lim) {
    int wv = off + ((blockIdx.x * blockDim.x + threadIdx.x) >> 6);
    int lane = threadIdx.x & 63;
    if (wv >= lim) return;
    int half = lane >> 5, l5 = lane & 31;
    int beg = rp[wv], end = rp[wv + 1];
    const unsigned char* tb = t8 + 4 * l5;
    f32x2 aL[4], aH[4];
#pragma unroll
    for (int j = 0; j < 4; ++j) { aL[j] = (f32x2){0.f, 0.f}; aH[j] = (f32x2){0.f, 0.f}; }
    int deg = end - beg;
    int nfull = deg & ~15;
    int p = beg;
    for (; p < beg + nfull; p += 16) {
#pragma unroll
        for (int jj = 0; jj < 8; ++jj) {
            unsigned e = cv[p + 2 * jj + half];
            unsigned v = *(const unsigned*)(tb + ((size_t)(e & 0x1FFFF) << 7));
            float w = __half2float(__ushort_as_half((unsigned short)(e >> 17)));
            f32x2 w2 = {w, w};
            f32x2 lo = __builtin_amdgcn_cvt_pk_f32_fp8((int)v, false);
            f32x2 hi = __builtin_amdgcn_cvt_pk_f32_fp8((int)v, true);
            aL[jj & 3] = lo * w2 + aL[jj & 3];
            aH[jj & 3] = hi * w2 + aH[jj & 3];
        }
    }
    if (p < end) {
        int last = end - 1;
#pragma unroll
        for (int jj = 0; jj < 8; ++jj) {
            int idx = p + 2 * jj + half;
            unsigned e = cv[min(idx, last)];
            unsigned v = *(const unsigned*)(tb + ((size_t)(e & 0x1FFFF) << 7));
            float w = __half2float(__ushort_as_half((unsigned short)(e >> 17)));
            w = (idx < end) ? w : 0.f;
            f32x2 w2 = {w, w};
            f32x2 lo = __builtin_amdgcn_cvt_pk_f32_fp8((int)v, false);
            f32x2 hi = __builtin_amdgcn_cvt_pk_f32_fp8((int)v, true);
            aL[jj & 3] = lo * w2 + aL[jj & 3];
            aH[jj & 3] = hi * w2 + aH[jj & 3];
        }
    }
    f32x2 sL = (aL[0] + aL[1]) + (aL[2] + aL[3]);
    f32x2 sH = (aH[0] + aH[1]) + (aH[2] + aH[3]);
    float s0 = sL[0], s1 = sL[1], s2 = sH[0], s3 = sH[1];
    s0 += __shfl_xor(s0, 32, 64);
    s1 += __shfl_xor(s1, 32, 64);
    s2 += __shfl_xor(s2, 32, 64);
    s3 += __shfl_xor(s3, 32, 64);
    if (half == 0) {
        float dd = dis[wv];
        float4 b = *(const float4*)&bias[4 * l5];
        float r0 = fmaxf(fmaf(dd, s0, b.x), 0.f);
        float r1 = fmaxf(fmaf(dd, s1, b.y), 0.f);
        float r2 = fmaxf(fmaf(dd, s2, b.z), 0.f);
        float r3 = fmaxf(fmaf(dd, s3, b.w), 0.f);
        uint2 pk;
        pk.x = pack2h(r0, r1);
        pk.y = pack2h(r2, r3);
        *(uint2*)&out[(size_t)wv * FEAT + 4 * l5] = pk;
    }
}

// ---------------- layer-2 prop fused with head projection (fp8 t), range [off,lim) ----------------
// z[i] = dis[i] * (relu(dis[i]*((A+I)@t)[i] + b1) @ Wc)
__global__ __launch_bounds__(256) void prop_zk_kernel(const int* __restrict__ rp,
                                                      const unsigned* __restrict__ cv,
                                                      const float* __restrict__ dis,
                                                      const unsigned char* __restrict__ t8,
                                                      const float* __restrict__ bias,
                                                      const float* __restrict__ Wc,
                                                      float* __restrict__ z,
                                                      int off, int lim) {
    int wv = off + ((blockIdx.x * blockDim.x + threadIdx.x) >> 6);
    int lane = threadIdx.x & 63;
    if (wv >= lim) return;
    int half = lane >> 5, l5 = lane & 31;
    int beg = rp[wv], end = rp[wv + 1];
    const unsigned char* tb = t8 + 4 * l5;
    f32x2 aL[4], aH[4];
#pragma unroll
    for (int j = 0; j < 4; ++j) { aL[j] = (f32x2){0.f, 0.f}; aH[j] = (f32x2){0.f, 0.f}; }
    int deg = end - beg;
    int nfull = deg & ~15;
    int p = beg;
    for (; p < beg + nfull; p += 16) {
#pragma unroll
        for (int jj = 0; jj < 8; ++jj) {
            unsigned e = cv[p + 2 * jj + half];
            unsigned v = *(const unsigned*)(tb + ((size_t)(e & 0x1FFFF) << 7));
            float w = __half2float(__ushort_as_half((unsigned short)(e >> 17)));
            f32x2 w2 = {w, w};
            f32x2 lo = __builtin_amdgcn_cvt_pk_f32_fp8((int)v, false);
            f32x2 hi = __builtin_amdgcn_cvt_pk_f32_fp8((int)v, true);
            aL[jj & 3] = lo * w2 + aL[jj & 3];
            aH[jj & 3] = hi * w2 + aH[jj & 3];
        }
    }
    if (p < end) {
        int last = end - 1;
#pragma unroll
        for (int jj = 0; jj < 8; ++jj) {
            int idx = p + 2 * jj + half;
            unsigned e = cv[min(idx, last)];
            unsigned v = *(const unsigned*)(tb + ((size_t)(e & 0x1FFFF) << 7));
            float w = __half2float(__ushort_as_half((unsigned short)(e >> 17)));
            w = (idx < end) ? w : 0.f;
            f32x2 w2 = {w, w};
            f32x2 lo = __builtin_amdgcn_cvt_pk_f32_fp8((int)v, false);
            f32x2 hi = __builtin_amdgcn_cvt_pk_f32_fp8((int)v, true);
            aL[jj & 3] = lo * w2 + aL[jj & 3];
            aH[jj & 3] = hi * w2 + aH[jj & 3];
        }
    }
    f32x2 sL = (aL[0] + aL[1]) + (aL[2] + aL[3]);
    f32x2 sH = (aH[0] + aH[1]) + (aH[2] + aH[3]);
    float s0 = sL[0], s1 = sL[1], s2 = sH[0], s3 = sH[1];
    s0 += __shfl_xor(s0, 32, 64);
    s1 += __shfl_xor(s1, 32, 64);
    s2 += __shfl_xor(s2, 32, 64);
    s3 += __shfl_xor(s3, 32, 64);
    float dd = dis[wv];
    float4 b = *(const float4*)&bias[4 * l5];
    float h0 = fmaxf(fmaf(dd, s0, b.x), 0.f);
    float h1 = fmaxf(fmaf(dd, s1, b.y), 0.f);
    float h2 = fmaxf(fmaf(dd, s2, b.z), 0.f);
    float h3 = fmaxf(fmaf(dd, s3, b.w), 0.f);
    float4 w0 = *(const float4*)&Wc[16 * l5];
    float4 w1 = *(const float4*)&Wc[16 * l5 + 4];
    float4 w2 = *(const float4*)&Wc[16 * l5 + 8];
    float4 w3 = *(const float4*)&Wc[16 * l5 + 12];
    float4 par;
    par.x = fmaf(h0, w0.x, fmaf(h1, w1.x, fmaf(h2, w2.x, h3 * w3.x)));
    par.y = fmaf(h0, w0.y, fmaf(h1, w1.y, fmaf(h2, w2.y, h3 * w3.y)));
    par.z = fmaf(h0, w0.z, fmaf(h1, w1.z, fmaf(h2, w2.z, h3 * w3.z)));
    par.w = fmaf(h0, w0.w, fmaf(h1, w1.w, fmaf(h2, w2.w, h3 * w3.w)));
#pragma unroll
    for (int mask = 1; mask < 32; mask <<= 1) {
        par.x += __shfl_xor(par.x, mask, 64);
        par.y += __shfl_xor(par.y, mask, 64);
        par.z += __shfl_xor(par.z, mask, 64);
        par.w += __shfl_xor(par.w, mask, 64);
    }
    if (lane == 0) {
        par.x *= dd; par.y *= dd; par.z *= dd; par.w *= dd;   // outer dis for layer-3 prop
        *(float4*)&z[(size_t)wv * 4] = par;
    }
}

// ---------------- CSR propagate, 4 feats: thread/node, 4 edges in flight ----------------
__global__ __launch_bounds__(256) void prop4_kernel(const int* __restrict__ rp,
                                                    const unsigned* __restrict__ cv,
                                                    const float* __restrict__ dis,
                                                    const float* __restrict__ z,
                                                    float* __restrict__ z2, int n) {
    int i = blockIdx.x * blockDim.x + threadIdx.x;
    if (i >= n) return;
    int beg = rp[i], end = rp[i + 1], last = end - 1;
    float4 a[4];
#pragma unroll
    for (int j = 0; j < 4; ++j) a[j] = (float4){0.f, 0.f, 0.f, 0.f};
    for (int p = beg; p < end; p += 4) {
#pragma unroll
        for (int j = 0; j < 4; ++j) {
            int idx = p + j;
            unsigned e = cv[min(idx, last)];
            float wq = __half2float(__ushort_as_half((unsigned short)(e >> 17)));
            wq = (idx < end) ? wq : 0.f;
            float4 v = *(const float4*)&z[(size_t)(e & 0x1FFFF) * 4];
            a[j].x = fmaf(v.x, wq, a[j].x); a[j].y = fmaf(v.y, wq, a[j].y);
            a[j].z = fmaf(v.z, wq, a[j].z); a[j].w = fmaf(v.w, wq, a[j].w);
        }
    }
    float dd = dis[i];
    float4 r;
    r.x = dd * ((a[0].x + a[1].x) + (a[2].x + a[3].x));
    r.y = dd * ((a[0].y + a[1].y) + (a[2].y + a[3].y));
    r.z = dd * ((a[0].z + a[1].z) + (a[2].z + a[3].z));
    r.w = dd * ((a[0].w + a[1].w) + (a[2].w + a[3].w));
    *(float4*)&z2[(size_t)i * 4] = r;
}

// ---------------- segment mean-pool on 4 feats + bias -> out[G x 4] ----------------
__global__ __launch_bounds__(256) void pool4_kernel(const float* __restrict__ z2,
                                                    const int* __restrict__ gstart,
                                                    const float* __restrict__ bc,
                                                    float* __restrict__ out, int G_) {
    __shared__ float sd[256];
    int g = blockIdx.x;
    int k = threadIdx.x & 3;
    int sub = threadIdx.x >> 2;
    int beg = gstart[g], end = gstart[g + 1];
    float s = 0.f;
    for (int i = beg + sub; i < end; i += 64) s += z2[(size_t)i * 4 + k];
    sd[threadIdx.x] = s;
    __syncthreads();
    for (int off = 32; off > 0; off >>= 1) {
        if (sub < off) sd[threadIdx.x] += sd[threadIdx.x + off * 4];
        __syncthreads();
    }
    if (sub == 0) {
        int c = end - beg;
        out[g * 4 + k] = sd[k] / (float)max(c, 1) + bc[k];
    }
}

extern "C" void kernel_launch(void* const* d_in, const int* in_sizes, int n_in,
                              void* d_out, int out_size, void* d_ws, size_t ws_size,
                              hipStream_t stream) {
    const float* x    = (const float*)d_in[0];
    const int*   ei   = (const int*)d_in[1];
    const float* eatt = (const float*)d_in[2];
    const int*   batch= (const int*)d_in[3];
    const float* W0   = (const float*)d_in[4];
    const float* b0   = (const float*)d_in[5];
    const float* W1   = (const float*)d_in[6];
    const float* b1   = (const float*)d_in[7];
    const float* W2   = (const float*)d_in[8];
    const float* b2   = (const float*)d_in[9];
    const float* Wp   = (const float*)d_in[10];
    const float* bp   = (const float*)d_in[11];
    float* out = (float*)d_out;

    const int Nn = in_sizes[0] / FEAT;        // 100000
    const int E_ = in_sizes[2];               // 1600000
    const int G_ = out_size / 4;              // 500
    const int NNZ = E_ + Nn;
    const int NB = ((Nn - 1) >> BSH) + 1;     // 391 buckets

    const int* e_src = ei;
    const int* e_dst = ei + E_;

    // ---- workspace layout ----
    char* ws = (char*)d_ws;
    size_t off = 0;
    auto alloc = [&](size_t bytes) { void* p = ws + off; off = (off + bytes + 255) & ~(size_t)255; return p; };
    float* dis     = (float*)alloc((size_t)Nn * 4);
    int*   rp      = (int*)  alloc((size_t)(Nn + 1) * 4);
    int*   gcnt    = (int*)  alloc((size_t)NB * 4);
    unsigned* cv   = (unsigned*)alloc((size_t)NNZ * 4);
    unsigned short* bufA = (unsigned short*)alloc((size_t)NB * BCAP * 8);  // h1 f16; aliases bins (25.6 MB)
    unsigned char* bufB8 = (unsigned char*)alloc((size_t)Nn * FEAT);       // t1/t2 fp8 (12.8 MB)
    int*   gstart  = (int*)  alloc((size_t)(G_ + 1) * 4);
    float* z       = (float*)alloc((size_t)Nn * 4 * 4);
    float* z2      = (float*)alloc((size_t)Nn * 4 * 4);
    float* Wc      = (float*)alloc(512 * 4);
    float* bc      = (float*)alloc(4 * 4);
    _Float16* Wt0  = (_Float16*)alloc(128 * 128 * 2);
    _Float16* Wt1  = (_Float16*)alloc(128 * 128 * 2);
    int2*  bins    = (int2*)bufA;   // dead before prop1 writes bufA
    (void)ws_size;

    const int T = 256;
    auto cdiv = [](int a, int b) { return (a + b - 1) / b; };
    const int half1 = (Nn + 1) / 2;

    // merged tiny preps (Wt0, Wt1, Wc/bc, gcnt zero, gstart)
    prep_kernel<<<129 + cdiv(Nn, T), T, 0, stream>>>(W0, W1, W2, Wp, b2, bp, batch,
                                                     Wt0, Wt1, Wc, bc, gstart, gcnt,
                                                     Nn, G_, NB);

    // CSR build: bin (LDS-staged, 1563 blocks) -> fused build (LDS-staged coalesced cv)
    bin1_kernel<<<cdiv(E_, 1024), T, 0, stream>>>(e_src, e_dst, eatt, gcnt, bins, E_, NB);
    buildcsr_kernel<<<NB, T, 0, stream>>>(bins, gcnt, rp, dis, cv, Nn);

    // layer 1: bufB8 = fp8(dis .* (x@W0)) via MFMA; bufA = f16(relu(dis .* ((A+I)@bufB8) + b0))
    gemm1_mfma<<<cdiv(Nn, 64), T, 0, stream>>>(x, Wt0, dis, bufB8, Nn);
    prop_kernel<<<cdiv(half1 * 64, T), T, 0, stream>>>(rp, cv, dis, bufB8, b0, bufA, 0, half1);
    prop_kernel<<<cdiv((Nn - half1) * 64, T), T, 0, stream>>>(rp, cv, dis, bufB8, b0, bufA, half1, Nn);

    // layer 2 + head fused: bufB8 = fp8(dis .* (bufA@W1)); z = dis .* (relu(...)@Wc)
    gemm2_mfma<<<cdiv(Nn, 64), T, 0, stream>>>(bufA, Wt1, dis, bufB8, Nn);
    prop_zk_kernel<<<cdiv(half1 * 64, T), T, 0, stream>>>(rp, cv, dis, bufB8, b1, Wc, z, 0, half1);
    prop_zk_kernel<<<cdiv((Nn - half1) * 64, T), T, 0, stream>>>(rp, cv, dis, bufB8, b1, Wc, z, half1, Nn);

    // layer 3 + pool
    prop4_kernel<<<cdiv(Nn, T), T, 0, stream>>>(rp, cv, dis, z, z2, Nn);
    pool4_kernel<<<G_, T, 0, stream>>>(z2, gstart, bc, out, G_);
}

// Round 10
// 316.953 us; speedup vs baseline: 1.1263x; 1.1041x over previous
//
#include <hip/hip_runtime.h>
#include <hip/hip_bf16.h>
#include <hip/hip_fp16.h>

// GCN, dis-folded: A_norm = D^-1/2 (A_w + I) D^-1/2; CSR stores raw w.
// R22: revert bin1 to CHUNK=4096 (R21's 1024-chunk quadrupled per-block O(NB)
//      overhead + same-line gcnt atomic contention: 25->60 us). Keep R21's
//      LDS-staged GEMMs (they left the top-5: the structural pipeline fix
//      worked). Props/buildcsr unchanged.

#define FEAT 128
#define BSH 8                 // bucket shift
#define BCAP 8192             // entries per bucket (mean 4092)

typedef union { int2 i2; long long u; struct { int s; float w; } e; } EdgePair;
typedef union { unsigned u; __half2 h2; } H2U;
typedef _Float16 f16x8 __attribute__((ext_vector_type(8)));
typedef float f32x4 __attribute__((ext_vector_type(4)));
typedef float f32x2 __attribute__((ext_vector_type(2)));

__device__ __forceinline__ unsigned pack2h(float a, float b) {
    return (unsigned)__half_as_ushort(__float2half_rn(a)) |
           ((unsigned)__half_as_ushort(__float2half_rn(b)) << 16);   // RNE both
}

__device__ __forceinline__ unsigned char to_fp8(float v) {
    int pk = __builtin_amdgcn_cvt_pk_fp8_f32(v, v, 0, false);   // RNE, sat
    return (unsigned char)(pk & 0xFF);
}

// ---------------- pass 1: bin edges by dst>>8, LDS-staged coalesced output ----------------
__global__ __launch_bounds__(256) void bin1_kernel(const int* __restrict__ src,
                                                   const int* __restrict__ dst,
                                                   const float* __restrict__ w,
                                                   int* __restrict__ gcnt,
                                                   int2* __restrict__ bins,
                                                   int E_, int NB) {
    __shared__ int lh[392], lofs[392], lbase[392], lcur[392];
    __shared__ unsigned sU[4096];
    __shared__ float    sW[4096];
    __shared__ unsigned short sB[4096];
    const int CHUNK = 4096;
    int base = blockIdx.x * CHUNK;
    int tid = threadIdx.x;
    for (int t = tid; t < NB; t += 256) { lh[t] = 0; lcur[t] = 0; }
    __syncthreads();
    int ds[16];
#pragma unroll
    for (int j = 0; j < 16; ++j) {
        int e = base + j * 256 + tid;
        ds[j] = (e < E_) ? dst[e] : -1;
        if (ds[j] >= 0) atomicAdd(&lh[ds[j] >> BSH], 1);
    }
    __syncthreads();
    // parallel exclusive prefix: thread t sums lh[0..t-1] (loads pipeline)
    for (int t = tid; t < NB; t += 256) {
        int run = 0;
        for (int i = 0; i < t; ++i) run += lh[i];
        lofs[t] = run;
    }
    __syncthreads();
    for (int t = tid; t < NB; t += 256)
        if (lh[t] > 0) lbase[t] = atomicAdd(&gcnt[t], lh[t]);
    __syncthreads();
    // place edges compactly into LDS staging, bucket-sorted
#pragma unroll
    for (int j = 0; j < 16; ++j) {
        int e = base + j * 256 + tid;
        if (ds[j] >= 0) {
            int b = ds[j] >> BSH;
            int r = atomicAdd(&lcur[b], 1);
            int s = lofs[b] + r;
            sU[s] = (unsigned)src[e] | ((unsigned)(ds[j] & 255) << 20);
            sW[s] = w[e];
            sB[s] = (unsigned short)b;
        }
    }
    __syncthreads();
    // linear copy-out: consecutive threads -> consecutive slots of each bucket run
    int total = min(CHUNK, E_ - base);
    for (int s = tid; s < total; s += 256) {
        int b = sB[s];
        int g = lbase[b] + (s - lofs[b]);
        if (g < BCAP) {
            int2 val; val.x = (int)sU[s]; val.y = __float_as_int(sW[s]);
            bins[(size_t)b * BCAP + g] = val;
        }
    }
}

// ---------------- fused CSR build: self-prefix + histogram + scan + rp/dis +
//                  LDS-staged scatter + coalesced copy-out ----------------
// cv entry: (f16bits(w) << 17) | src   (w in [0,1] -> f16 bits <= 0x3C00, 15 bits)
__global__ __launch_bounds__(256) void buildcsr_kernel(const int2* __restrict__ bins,
                                                       const int* __restrict__ gcnt,
                                                       int* __restrict__ rp,
                                                       float* __restrict__ dis,
                                                       unsigned* __restrict__ cv, int n) {
    __shared__ int lh[256];
    __shared__ float wsum[256];
    __shared__ int sc[256];
    __shared__ int lcur[256];
    __shared__ int red[256];
    __shared__ unsigned scv[BCAP + 256];
    int b = blockIdx.x;
    int tid = threadIdx.x;
    int node0 = b << BSH;
    int node = node0 + tid;
    bool valid = node < n;
    lh[tid] = 0;
    wsum[tid] = 1.0f;   // self-loop weight
    // self-computed exclusive prefix over buckets < b (gcnt L2-hot after bin1)
    int part = 0;
    for (int i = tid; i < b; i += 256)
        part += min(gcnt[i], BCAP) + min(256, n - (i << BSH));
    red[tid] = part;
    __syncthreads();
    for (int off = 128; off > 0; off >>= 1) {
        if (tid < off) red[tid] += red[tid + off];
        __syncthreads();
    }
    int base = red[0];
    int m = min(gcnt[b], BCAP);
    int nvalid = min(256, n - node0);
    if (b == (int)gridDim.x - 1 && tid == 0)
        rp[n] = base + m + nvalid;
    const int2* bp = bins + (size_t)b * BCAP;
    for (int i = tid; i < m; i += 256) {
        int2 raw = bp[i];
        unsigned pk = (unsigned)raw.x;
        int dlo = pk >> 20;
        atomicAdd(&lh[dlo], 1);
        atomicAdd(&wsum[dlo], __int_as_float(raw.y));
    }
    __syncthreads();
    int cnt_t = valid ? (lh[tid] + 1) : 0;   // +1 self-loop
    sc[tid] = cnt_t;
    __syncthreads();
    for (int off = 1; off < 256; off <<= 1) {
        int x = (tid >= off) ? sc[tid - off] : 0;
        __syncthreads();
        sc[tid] += x;
        __syncthreads();
    }
    int excl = sc[tid] - cnt_t;
    if (valid) {
        rp[node] = base + excl;
        dis[node] = rsqrtf(fmaxf(wsum[tid], 1e-12f));
    }
    lcur[tid] = excl;                        // LOCAL positions for staging
    __syncthreads();
    for (int i = tid; i < m; i += 256) {
        int2 raw = bp[i];                    // second read: L2-hot
        unsigned pk = (unsigned)raw.x;
        int dlo = pk >> 20;
        int pos = atomicAdd(&lcur[dlo], 1);
        unsigned hw = (unsigned)__half_as_ushort(__float2half_rn(__int_as_float(raw.y)));
        scv[pos] = (hw << 17) | (pk & 0x1FFFF);
    }
    __syncthreads();
    if (valid) {                             // self-loop entry, w = 1 -> f16 0x3C00
        int pos = atomicAdd(&lcur[tid], 1);
        scv[pos] = (0x3C00u << 17) | (unsigned)node;
    }
    __syncthreads();
    // contiguous coalesced copy-out of the whole bucket range
    int total = m + nvalid;
    for (int s = tid; s < total; s += 256)
        cv[base + s] = scv[s];
}

// ---------------- merged tiny preps ----------------
// blocks [0,64): Wt0; [64,128): Wt1; 128: Wc+bc+gcnt-zero; [129, 129+nbg): gbound
__global__ __launch_bounds__(256) void prep_kernel(const float* __restrict__ W0,
                                                   const float* __restrict__ W1,
                                                   const float* __restrict__ W2,
                                                   const float* __restrict__ Wp,
                                                   const float* __restrict__ b2,
                                                   const float* __restrict__ bp,
                                                   const int* __restrict__ batch,
                                                   _Float16* __restrict__ Wt0,
                                                   _Float16* __restrict__ Wt1,
                                                   float* __restrict__ Wc,
                                                   float* __restrict__ bc,
                                                   int* __restrict__ gstart,
                                                   int* __restrict__ gcnt,
                                                   int n, int G_, int NB) {
    int blk = blockIdx.x;
    if (blk < 64) {
        int tid = blk * 256 + threadIdx.x;
        int nn = tid >> 7, k = tid & 127;
        Wt0[nn * 128 + k] = (_Float16)W0[k * 128 + nn];
    } else if (blk < 128) {
        int tid = (blk - 64) * 256 + threadIdx.x;
        int nn = tid >> 7, k = tid & 127;
        Wt1[nn * 128 + k] = (_Float16)W1[k * 128 + nn];
    } else if (blk == 128) {
        for (int tid = threadIdx.x; tid < 512; tid += 256) {
            int c = tid >> 2, k = tid & 3;
            float s = 0.f;
            for (int j = 0; j < 200; ++j) s = fmaf(W2[c * 200 + j], Wp[j * 4 + k], s);
            Wc[tid] = s;
        }
        if (threadIdx.x < 4) {
            float s = bp[threadIdx.x];
            for (int j = 0; j < 200; ++j) s = fmaf(b2[j], Wp[j * 4 + threadIdx.x], s);
            bc[threadIdx.x] = s;
        }
        for (int i = threadIdx.x; i < NB; i += 256) gcnt[i] = 0;
    } else {
        int i = (blk - 129) * 256 + threadIdx.x;
        if (i >= n) return;
        int b = batch[i];
        int prev = (i == 0) ? -1 : batch[i - 1];
        for (int g = prev + 1; g <= b; ++g) gstart[g] = i;
        if (i == n - 1) {
            for (int g = b + 1; g <= G_; ++g) gstart[g] = n;
        }
    }
}

// ---------------- MFMA GEMM: C_fp8[M x 128] = rowscale .* (A @ W), Wt[n][k] f16 ----------------
// Wt staged in LDS (XOR-swizzled: byte ^= (row&7)<<4 -> strided b128 reads are
// 2-way conflict (free) instead of 16-way). A-loads issued before staging so
// HBM latency hides under stage+sync; first t-iteration needs all af[kc] ->
// all 8 loads forced in flight. Same FMA order -> bit-identical output.
__global__ __launch_bounds__(256, 4) void gemm1_mfma(const float* __restrict__ A,
                                                     const _Float16* __restrict__ Wt,
                                                     const float* __restrict__ rowscale,
                                                     unsigned char* __restrict__ C, int M) {
    __shared__ _Float16 sWt[128 * 128];
    int tid = threadIdx.x;
    int wid = tid >> 6, lane = tid & 63;
    int quad = lane >> 4, l16 = lane & 15;
    int row0 = blockIdx.x * 64 + wid * 16;
    int arow = row0 + l16; if (arow >= M) arow = M - 1;   // clamp: pollutes only discarded D rows
    const float* abase = A + (size_t)arow * 128 + quad * 8;
    float4 a0[4], a1[4];
#pragma unroll
    for (int kc = 0; kc < 4; ++kc) {            // 8 loads issued before staging
        a0[kc] = *(const float4*)(abase + kc * 32);
        a1[kc] = *(const float4*)(abase + kc * 32 + 4);
    }
    {   // stage Wt -> LDS, swizzled
        const char* s = (const char*)Wt;
        char* d = (char*)sWt;
#pragma unroll
        for (int j = 0; j < 8; ++j) {
            int o = (tid + j * 256) * 16;                    // linear byte offset
            int so = o ^ (((o >> 8) & 7) << 4);              // (row&7)<<4
            *(uint4*)(d + so) = *(const uint4*)(s + o);
        }
    }
    __syncthreads();
    f16x8 af[4];
#pragma unroll
    for (int kc = 0; kc < 4; ++kc)
        af[kc] = (f16x8){ (_Float16)a0[kc].x, (_Float16)a0[kc].y, (_Float16)a0[kc].z, (_Float16)a0[kc].w,
                          (_Float16)a1[kc].x, (_Float16)a1[kc].y, (_Float16)a1[kc].z, (_Float16)a1[kc].w };
    f32x4 acc[8];
#pragma unroll
    for (int t = 0; t < 8; ++t) acc[t] = (f32x4){0.f, 0.f, 0.f, 0.f};
    const char* wb = (const char*)sWt;
    int xorv = (l16 & 7) << 4;
#pragma unroll
    for (int t = 0; t < 8; ++t) {
        f16x8 bf[4];
#pragma unroll
        for (int kc = 0; kc < 4; ++kc) {
            int o = (((t * 16 + l16) * 128 + quad * 8 + kc * 32) * 2) ^ xorv;
            bf[kc] = *(const f16x8*)(wb + o);
        }
#pragma unroll
        for (int kc = 0; kc < 4; ++kc)
            acc[t] = __builtin_amdgcn_mfma_f32_16x16x32_f16(af[kc], bf[kc], acc[t], 0, 0, 0);
    }
    int orow0 = row0 + quad * 4;
#pragma unroll
    for (int r = 0; r < 4; ++r) {
        int orow = orow0 + r;
        if (orow < M) {
            float sc = rowscale[orow];
#pragma unroll
            for (int t = 0; t < 8; ++t)
                C[(size_t)orow * 128 + t * 16 + l16] = to_fp8(acc[t][r] * sc);
        }
    }
}

__global__ __launch_bounds__(256, 4) void gemm2_mfma(const unsigned short* __restrict__ A,
                                                     const _Float16* __restrict__ Wt,
                                                     const float* __restrict__ rowscale,
                                                     unsigned char* __restrict__ C, int M) {
    __shared__ _Float16 sWt[128 * 128];
    int tid = threadIdx.x;
    int wid = tid >> 6, lane = tid & 63;
    int quad = lane >> 4, l16 = lane & 15;
    int row0 = blockIdx.x * 64 + wid * 16;
    int arow = row0 + l16; if (arow >= M) arow = M - 1;
    const _Float16* abase = (const _Float16*)A + (size_t)arow * 128 + quad * 8;
    f16x8 af[4];
#pragma unroll
    for (int kc = 0; kc < 4; ++kc)              // 4 loads issued before staging
        af[kc] = *(const f16x8*)(abase + kc * 32);
    {   // stage Wt -> LDS, swizzled
        const char* s = (const char*)Wt;
        char* d = (char*)sWt;
#pragma unroll
        for (int j = 0; j < 8; ++j) {
            int o = (tid + j * 256) * 16;
            int so = o ^ (((o >> 8) & 7) << 4);
            *(uint4*)(d + so) = *(const uint4*)(s + o);
        }
    }
    __syncthreads();
    f32x4 acc[8];
#pragma unroll
    for (int t = 0; t < 8; ++t) acc[t] = (f32x4){0.f, 0.f, 0.f, 0.f};
    const char* wb = (const char*)sWt;
    int xorv = (l16 & 7) << 4;
#pragma unroll
    for (int t = 0; t < 8; ++t) {
        f16x8 bf[4];
#pragma unroll
        for (int kc = 0; kc < 4; ++kc) {
            int o = (((t * 16 + l16) * 128 + quad * 8 + kc * 32) * 2) ^ xorv;
            bf[kc] = *(const f16x8*)(wb + o);
        }
#pragma unroll
        for (int kc = 0; kc < 4; ++kc)
            acc[t] = __builtin_amdgcn_mfma_f32_16x16x32_f16(af[kc], bf[kc], acc[t], 0, 0, 0);
    }
    int orow0 = row0 + quad * 4;
#pragma unroll
    for (int r = 0; r < 4; ++r) {
        int orow = orow0 + r;
        if (orow < M) {
            float sc = rowscale[orow];
#pragma unroll
            for (int t = 0; t < 8; ++t)
                C[(size_t)orow * 128 + t * 16 + l16] = to_fp8(acc[t][r] * sc);
        }
    }
}

// ---------------- CSR propagate, 128 fp8 feats (layer 1), node range [off,lim) ----------------
// wave/node; half-wave per edge, 32 lanes x 4 fp8. Full 16-edge rounds carry
// no clamp/cndmask; only the tail round does. f32x2 packed accumulate.
__global__ __launch_bounds__(256) void prop_kernel(const int* __restrict__ rp,
                                                   const unsigned* __restrict__ cv,
                                                   const float* __restrict__ dis,
                                                   const unsigned char* __restrict__ t8,
                                                   const float* __restrict__ bias,
                                                   unsigned short* __restrict__ out,
                                                   int off, int lim) {
    int wv = off + ((blockIdx.x * blockDim.x + threadIdx.x) >> 6);
    int lane = threadIdx.x & 63;
    if (wv >= lim) return;
    int half = lane >> 5, l5 = lane & 31;
    int beg = rp[wv], end = rp[wv + 1];
    const unsigned char* tb = t8 + 4 * l5;
    f32x2 aL[4], aH[4];
#pragma unroll
    for (int j = 0; j < 4; ++j) { aL[j] = (f32x2){0.f, 0.f}; aH[j] = (f32x2){0.f, 0.f}; }
    int deg = end - beg;
    int nfull = deg & ~15;
    int p = beg;
    for (; p < beg + nfull; p += 16) {
#pragma unroll
        for (int jj = 0; jj < 8; ++jj) {
            unsigned e = cv[p + 2 * jj + half];
            unsigned v = *(const unsigned*)(tb + ((size_t)(e & 0x1FFFF) << 7));
            float w = __half2float(__ushort_as_half((unsigned short)(e >> 17)));
            f32x2 w2 = {w, w};
            f32x2 lo = __builtin_amdgcn_cvt_pk_f32_fp8((int)v, false);
            f32x2 hi = __builtin_amdgcn_cvt_pk_f32_fp8((int)v, true);
            aL[jj & 3] = lo * w2 + aL[jj & 3];
            aH[jj & 3] = hi * w2 + aH[jj & 3];
        }
    }
    if (p < end) {
        int last = end - 1;
#pragma unroll
        for (int jj = 0; jj < 8; ++jj) {
            int idx = p + 2 * jj + half;
            unsigned e = cv[min(idx, last)];
            unsigned v = *(const unsigned*)(tb + ((size_t)(e & 0x1FFFF) << 7));
            float w = __half2float(__ushort_as_half((unsigned short)(e >> 17)));
            w = (idx < end) ? w : 0.f;
            f32x2 w2 = {w, w};
            f32x2 lo = __builtin_amdgcn_cvt_pk_f32_fp8((int)v, false);
            f32x2 hi = __builtin_amdgcn_cvt_pk_f32_fp8((int)v, true);
            aL[jj & 3] = lo * w2 + aL[jj & 3];
            aH[jj & 3] = hi * w2 + aH[jj & 3];
        }
    }
    f32x2 sL = (aL[0] + aL[1]) + (aL[2] + aL[3]);
    f32x2 sH = (aH[0] + aH[1]) + (aH[2] + aH[3]);
    float s0 = sL[0], s1 = sL[1], s2 = sH[0], s3 = sH[1];
    s0 += __shfl_xor(s0, 32, 64);
    s1 += __shfl_xor(s1, 32, 64);
    s2 += __shfl_xor(s2, 32, 64);
    s3 += __shfl_xor(s3, 32, 64);
    if (half == 0) {
        float dd = dis[wv];
        float4 b = *(const float4*)&bias[4 * l5];
        float r0 = fmaxf(fmaf(dd, s0, b.x), 0.f);
        float r1 = fmaxf(fmaf(dd, s1, b.y), 0.f);
        float r2 = fmaxf(fmaf(dd, s2, b.z), 0.f);
        float r3 = fmaxf(fmaf(dd, s3, b.w), 0.f);
        uint2 pk;
        pk.x = pack2h(r0, r1);
        pk.y = pack2h(r2, r3);
        *(uint2*)&out[(size_t)wv * FEAT + 4 * l5] = pk;
    }
}

// ---------------- layer-2 prop fused with head projection (fp8 t), range [off,lim) ----------------
// z[i] = dis[i] * (relu(dis[i]*((A+I)@t)[i] + b1) @ Wc)
__global__ __launch_bounds__(256) void prop_zk_kernel(const int* __restrict__ rp,
                                                      const unsigned* __restrict__ cv,
                                                      const float* __restrict__ dis,
                                                      const unsigned char* __restrict__ t8,
                                                      const float* __restrict__ bias,
                                                      const float* __restrict__ Wc,
                                                      float* __restrict__ z,
                                                      int off, int lim) {
    int wv = off + ((blockIdx.x * blockDim.x + threadIdx.x) >> 6);
    int lane = threadIdx.x & 63;
    if (wv >= lim) return;
    int half = lane >> 5, l5 = lane & 31;
    int beg = rp[wv], end = rp[wv + 1];
    const unsigned char* tb = t8 + 4 * l5;
    f32x2 aL[4], aH[4];
#pragma unroll
    for (int j = 0; j < 4; ++j) { aL[j] = (f32x2){0.f, 0.f}; aH[j] = (f32x2){0.f, 0.f}; }
    int deg = end - beg;
    int nfull = deg & ~15;
    int p = beg;
    for (; p < beg + nfull; p += 16) {
#pragma unroll
        for (int jj = 0; jj < 8; ++jj) {
            unsigned e = cv[p + 2 * jj + half];
            unsigned v = *(const unsigned*)(tb + ((size_t)(e & 0x1FFFF) << 7));
            float w = __half2float(__ushort_as_half((unsigned short)(e >> 17)));
            f32x2 w2 = {w, w};
            f32x2 lo = __builtin_amdgcn_cvt_pk_f32_fp8((int)v, false);
            f32x2 hi = __builtin_amdgcn_cvt_pk_f32_fp8((int)v, true);
            aL[jj & 3] = lo * w2 + aL[jj & 3];
            aH[jj & 3] = hi * w2 + aH[jj & 3];
        }
    }
    if (p < end) {
        int last = end - 1;
#pragma unroll
        for (int jj = 0; jj < 8; ++jj) {
            int idx = p + 2 * jj + half;
            unsigned e = cv[min(idx, last)];
            unsigned v = *(const unsigned*)(tb + ((size_t)(e & 0x1FFFF) << 7));
            float w = __half2float(__ushort_as_half((unsigned short)(e >> 17)));
            w = (idx < end) ? w : 0.f;
            f32x2 w2 = {w, w};
            f32x2 lo = __builtin_amdgcn_cvt_pk_f32_fp8((int)v, false);
            f32x2 hi = __builtin_amdgcn_cvt_pk_f32_fp8((int)v, true);
            aL[jj & 3] = lo * w2 + aL[jj & 3];
            aH[jj & 3] = hi * w2 + aH[jj & 3];
        }
    }
    f32x2 sL = (aL[0] + aL[1]) + (aL[2] + aL[3]);
    f32x2 sH = (aH[0] + aH[1]) + (aH[2] + aH[3]);
    float s0 = sL[0], s1 = sL[1], s2 = sH[0], s3 = sH[1];
    s0 += __shfl_xor(s0, 32, 64);
    s1 += __shfl_xor(s1, 32, 64);
    s2 += __shfl_xor(s2, 32, 64);
    s3 += __shfl_xor(s3, 32, 64);
    float dd = dis[wv];
    float4 b = *(const float4*)&bias[4 * l5];
    float h0 = fmaxf(fmaf(dd, s0, b.x), 0.f);
    float h1 = fmaxf(fmaf(dd, s1, b.y), 0.f);
    float h2 = fmaxf(fmaf(dd, s2, b.z), 0.f);
    float h3 = fmaxf(fmaf(dd, s3, b.w), 0.f);
    float4 w0 = *(const float4*)&Wc[16 * l5];
    float4 w1 = *(const float4*)&Wc[16 * l5 + 4];
    float4 w2 = *(const float4*)&Wc[16 * l5 + 8];
    float4 w3 = *(const float4*)&Wc[16 * l5 + 12];
    float4 par;
    par.x = fmaf(h0, w0.x, fmaf(h1, w1.x, fmaf(h2, w2.x, h3 * w3.x)));
    par.y = fmaf(h0, w0.y, fmaf(h1, w1.y, fmaf(h2, w2.y, h3 * w3.y)));
    par.z = fmaf(h0, w0.z, fmaf(h1, w1.z, fmaf(h2, w2.z, h3 * w3.z)));
    par.w = fmaf(h0, w0.w, fmaf(h1, w1.w, fmaf(h2, w2.w, h3 * w3.w)));
#pragma unroll
    for (int mask = 1; mask < 32; mask <<= 1) {
        par.x += __shfl_xor(par.x, mask, 64);
        par.y += __shfl_xor(par.y, mask, 64);
        par.z += __shfl_xor(par.z, mask, 64);
        par.w += __shfl_xor(par.w, mask, 64);
    }
    if (lane == 0) {
        par.x *= dd; par.y *= dd; par.z *= dd; par.w *= dd;   // outer dis for layer-3 prop
        *(float4*)&z[(size_t)wv * 4] = par;
    }
}

// ---------------- CSR propagate, 4 feats: thread/node, 4 edges in flight ----------------
__global__ __launch_bounds__(256) void prop4_kernel(const int* __restrict__ rp,
                                                    const unsigned* __restrict__ cv,
                                                    const float* __restrict__ dis,
                                                    const float* __restrict__ z,
                                                    float* __restrict__ z2, int n) {
    int i = blockIdx.x * blockDim.x + threadIdx.x;
    if (i >= n) return;
    int beg = rp[i], end = rp[i + 1], last = end - 1;
    float4 a[4];
#pragma unroll
    for (int j = 0; j < 4; ++j) a[j] = (float4){0.f, 0.f, 0.f, 0.f};
    for (int p = beg; p < end; p += 4) {
#pragma unroll
        for (int j = 0; j < 4; ++j) {
            int idx = p + j;
            unsigned e = cv[min(idx, last)];
            float wq = __half2float(__ushort_as_half((unsigned short)(e >> 17)));
            wq = (idx < end) ? wq : 0.f;
            float4 v = *(const float4*)&z[(size_t)(e & 0x1FFFF) * 4];
            a[j].x = fmaf(v.x, wq, a[j].x); a[j].y = fmaf(v.y, wq, a[j].y);
            a[j].z = fmaf(v.z, wq, a[j].z); a[j].w = fmaf(v.w, wq, a[j].w);
        }
    }
    float dd = dis[i];
    float4 r;
    r.x = dd * ((a[0].x + a[1].x) + (a[2].x + a[3].x));
    r.y = dd * ((a[0].y + a[1].y) + (a[2].y + a[3].y));
    r.z = dd * ((a[0].z + a[1].z) + (a[2].z + a[3].z));
    r.w = dd * ((a[0].w + a[1].w) + (a[2].w + a[3].w));
    *(float4*)&z2[(size_t)i * 4] = r;
}

// ---------------- segment mean-pool on 4 feats + bias -> out[G x 4] ----------------
__global__ __launch_bounds__(256) void pool4_kernel(const float* __restrict__ z2,
                                                    const int* __restrict__ gstart,
                                                    const float* __restrict__ bc,
                                                    float* __restrict__ out, int G_) {
    __shared__ float sd[256];
    int g = blockIdx.x;
    int k = threadIdx.x & 3;
    int sub = threadIdx.x >> 2;
    int beg = gstart[g], end = gstart[g + 1];
    float s = 0.f;
    for (int i = beg + sub; i < end; i += 64) s += z2[(size_t)i * 4 + k];
    sd[threadIdx.x] = s;
    __syncthreads();
    for (int off = 32; off > 0; off >>= 1) {
        if (sub < off) sd[threadIdx.x] += sd[threadIdx.x + off * 4];
        __syncthreads();
    }
    if (sub == 0) {
        int c = end - beg;
        out[g * 4 + k] = sd[k] / (float)max(c, 1) + bc[k];
    }
}

extern "C" void kernel_launch(void* const* d_in, const int* in_sizes, int n_in,
                              void* d_out, int out_size, void* d_ws, size_t ws_size,
                              hipStream_t stream) {
    const float* x    = (const float*)d_in[0];
    const int*   ei   = (const int*)d_in[1];
    const float* eatt = (const float*)d_in[2];
    const int*   batch= (const int*)d_in[3];
    const float* W0   = (const float*)d_in[4];
    const float* b0   = (const float*)d_in[5];
    const float* W1   = (const float*)d_in[6];
    const float* b1   = (const float*)d_in[7];
    const float* W2   = (const float*)d_in[8];
    const float* b2   = (const float*)d_in[9];
    const float* Wp   = (const float*)d_in[10];
    const float* bp   = (const float*)d_in[11];
    float* out = (float*)d_out;

    const int Nn = in_sizes[0] / FEAT;        // 100000
    const int E_ = in_sizes[2];               // 1600000
    const int G_ = out_size / 4;              // 500
    const int NNZ = E_ + Nn;
    const int NB = ((Nn - 1) >> BSH) + 1;     // 391 buckets

    const int* e_src = ei;
    const int* e_dst = ei + E_;

    // ---- workspace layout ----
    char* ws = (char*)d_ws;
    size_t off = 0;
    auto alloc = [&](size_t bytes) { void* p = ws + off; off = (off + bytes + 255) & ~(size_t)255; return p; };
    float* dis     = (float*)alloc((size_t)Nn * 4);
    int*   rp      = (int*)  alloc((size_t)(Nn + 1) * 4);
    int*   gcnt    = (int*)  alloc((size_t)NB * 4);
    unsigned* cv   = (unsigned*)alloc((size_t)NNZ * 4);
    unsigned short* bufA = (unsigned short*)alloc((size_t)NB * BCAP * 8);  // h1 f16; aliases bins (25.6 MB)
    unsigned char* bufB8 = (unsigned char*)alloc((size_t)Nn * FEAT);       // t1/t2 fp8 (12.8 MB)
    int*   gstart  = (int*)  alloc((size_t)(G_ + 1) * 4);
    float* z       = (float*)alloc((size_t)Nn * 4 * 4);
    float* z2      = (float*)alloc((size_t)Nn * 4 * 4);
    float* Wc      = (float*)alloc(512 * 4);
    float* bc      = (float*)alloc(4 * 4);
    _Float16* Wt0  = (_Float16*)alloc(128 * 128 * 2);
    _Float16* Wt1  = (_Float16*)alloc(128 * 128 * 2);
    int2*  bins    = (int2*)bufA;   // dead before prop1 writes bufA
    (void)ws_size;

    const int T = 256;
    auto cdiv = [](int a, int b) { return (a + b - 1) / b; };
    const int half1 = (Nn + 1) / 2;

    // merged tiny preps (Wt0, Wt1, Wc/bc, gcnt zero, gstart)
    prep_kernel<<<129 + cdiv(Nn, T), T, 0, stream>>>(W0, W1, W2, Wp, b2, bp, batch,
                                                     Wt0, Wt1, Wc, bc, gstart, gcnt,
                                                     Nn, G_, NB);

    // CSR build: bin (LDS-staged, 391 blocks) -> fused build (LDS-staged coalesced cv)
    bin1_kernel<<<cdiv(E_, 4096), T, 0, stream>>>(e_src, e_dst, eatt, gcnt, bins, E_, NB);
    buildcsr_kernel<<<NB, T, 0, stream>>>(bins, gcnt, rp, dis, cv, Nn);

    // layer 1: bufB8 = fp8(dis .* (x@W0)) via MFMA; bufA = f16(relu(dis .* ((A+I)@bufB8) + b0))
    gemm1_mfma<<<cdiv(Nn, 64), T, 0, stream>>>(x, Wt0, dis, bufB8, Nn);
    prop_kernel<<<cdiv(half1 * 64, T), T, 0, stream>>>(rp, cv, dis, bufB8, b0, bufA, 0, half1);
    prop_kernel<<<cdiv((Nn - half1) * 64, T), T, 0, stream>>>(rp, cv, dis, bufB8, b0, bufA, half1, Nn);

    // layer 2 + head fused: bufB8 = fp8(dis .* (bufA@W1)); z = dis .* (relu(...)@Wc)
    gemm2_mfma<<<cdiv(Nn, 64), T, 0, stream>>>(bufA, Wt1, dis, bufB8, Nn);
    prop_zk_kernel<<<cdiv(half1 * 64, T), T, 0, stream>>>(rp, cv, dis, bufB8, b1, Wc, z, 0, half1);
    prop_zk_kernel<<<cdiv((Nn - half1) * 64, T), T, 0, stream>>>(rp, cv, dis, bufB8, b1, Wc, z, half1, Nn);

    // layer 3 + pool
    prop4_kernel<<<cdiv(Nn, T), T, 0, stream>>>(rp, cv, dis, z, z2, Nn);
    pool4_kernel<<<G_, T, 0, stream>>>(z2, gstart, bc, out, G_);
}